// Round 3
// baseline (574.280 us; speedup 1.0000x reference)
//
#include <hip/hip_runtime.h>

#define NN 100000
#define NE 1600000
#define NG 256
#define SCAN_CHUNK 1024
#define NB_SCAN ((NN + SCAN_CHUNK - 1) / SCAN_CHUNK)  // 98

// ---------------- degree histogram + edge rank (int4, 4 edges/thread) ----------------
__global__ void hist_rank_kernel(const int* __restrict__ dst, int* __restrict__ cnt,
                                 int* __restrict__ rank, int E4) {
    int t = blockIdx.x * blockDim.x + threadIdx.x;
    if (t >= E4) return;
    int4 d = ((const int4*)dst)[t];
    int4 r;
    r.x = atomicAdd(&cnt[d.x], 1);
    r.y = atomicAdd(&cnt[d.y], 1);
    r.z = atomicAdd(&cnt[d.z], 1);
    r.w = atomicAdd(&cnt[d.w], 1);
    ((int4*)rank)[t] = r;
}

// ---------------- exclusive scan (3 kernels); scan1 also emits deg_inv ----------------
__global__ __launch_bounds__(256) void scan1_kernel(const int* __restrict__ cnt,
                                                    int* __restrict__ part,
                                                    int* __restrict__ bsum,
                                                    float* __restrict__ deg_inv) {
    __shared__ int ts[256];
    int tid = threadIdx.x;
    int base = blockIdx.x * SCAN_CHUNK + tid * 4;
    int v[4];
    int s = 0;
#pragma unroll
    for (int i = 0; i < 4; ++i) {
        v[i] = (base + i < NN) ? cnt[base + i] : 0;
        if (base + i < NN) deg_inv[base + i] = rsqrtf(1.0f + (float)v[i]);
        s += v[i];
    }
    ts[tid] = s;
    __syncthreads();
    for (int off = 1; off < 256; off <<= 1) {
        int t = (tid >= off) ? ts[tid - off] : 0;
        __syncthreads();
        ts[tid] += t;
        __syncthreads();
    }
    int run = ts[tid] - s;  // exclusive prefix for this thread
#pragma unroll
    for (int i = 0; i < 4; ++i) {
        if (base + i < NN) part[base + i] = run;
        run += v[i];
    }
    if (tid == 255) bsum[blockIdx.x] = ts[255];
}

__global__ __launch_bounds__(128) void scan2_kernel(const int* __restrict__ bsum,
                                                    int* __restrict__ bsumex) {
    __shared__ int ts[128];
    int tid = threadIdx.x;
    int v = (tid < NB_SCAN) ? bsum[tid] : 0;
    ts[tid] = v;
    __syncthreads();
    for (int off = 1; off < 128; off <<= 1) {
        int t = (tid >= off) ? ts[tid - off] : 0;
        __syncthreads();
        ts[tid] += t;
        __syncthreads();
    }
    bsumex[tid] = ts[tid] - v;
}

__global__ __launch_bounds__(256) void scan3_kernel(const int* __restrict__ part,
                                                    const int* __restrict__ bsumex,
                                                    int* __restrict__ row_ptr) {
    int tid = threadIdx.x;
    int base = blockIdx.x * SCAN_CHUNK + tid * 4;
    int add = bsumex[blockIdx.x];
#pragma unroll
    for (int i = 0; i < 4; ++i) {
        int idx = base + i;
        if (idx < NN) row_ptr[idx] = part[idx] + add;
    }
    if (blockIdx.x == 0 && tid == 0) row_ptr[NN] = NE;
}

// ---------------- CSR fill: atomic-free scatter (4 edges/thread) ----------------
__global__ void fill_kernel(const int* __restrict__ src, const int* __restrict__ dst,
                            const int* __restrict__ rank, const int* __restrict__ row_ptr,
                            int* __restrict__ col, int E4) {
    int t = blockIdx.x * blockDim.x + threadIdx.x;
    if (t >= E4) return;
    int4 d = ((const int4*)dst)[t];
    int4 s = ((const int4*)src)[t];
    int4 r = ((const int4*)rank)[t];
    int p0 = row_ptr[d.x] + r.x;
    int p1 = row_ptr[d.y] + r.y;
    int p2 = row_ptr[d.z] + r.z;
    int p3 = row_ptr[d.w] + r.w;
    col[p0] = s.x;
    col[p1] = s.y;
    col[p2] = s.z;
    col[p3] = s.w;
}

// ---------------- GEMM1: [N,128] @ [128,32], epilogue scale by deg_inv ----------------
__global__ __launch_bounds__(256) void gemm_x_w1(const float* __restrict__ x,
                                                 const float* __restrict__ W,
                                                 const float* __restrict__ deg_inv,
                                                 float* __restrict__ h, int N) {
    __shared__ float wsh[128 * 32];
    __shared__ float xs[8][128];
    int tid = threadIdx.x;
    for (int i = tid; i < 128 * 32 / 4; i += 256)
        ((float4*)wsh)[i] = ((const float4*)W)[i];
    int row0 = blockIdx.x * 8;
    {
        int r = tid / 32, c4 = tid % 32;
        int row = row0 + r;
        float4 v = make_float4(0.f, 0.f, 0.f, 0.f);
        if (row < N) v = ((const float4*)x)[row * 32 + c4];
        ((float4*)xs[r])[c4] = v;
    }
    __syncthreads();
    int r = tid / 32, c = tid % 32;
    int row = row0 + r;
    float acc = 0.f;
#pragma unroll 8
    for (int k = 0; k < 128; ++k)
        acc += xs[r][k] * wsh[k * 32 + c];
    if (row < N) h[row * 32 + c] = acc * deg_inv[row];
}

// ---------------- gather conv F=32, one node per 32 lanes ----------------
// MODE 0 (layer1, fused rescale for layer2):  out[d] = di^2*acc + di*b[lane]
// MODE 1 (layer2 aggregation only):           out[d] = di*acc
template <int MODE>
__global__ __launch_bounds__(256) void conv32_kernel(const int* __restrict__ row_ptr,
                                                     const int* __restrict__ col,
                                                     const float* __restrict__ h_s,
                                                     const float* __restrict__ deg_inv,
                                                     const float* __restrict__ b,
                                                     float* __restrict__ out) {
    int gid = blockIdx.x * blockDim.x + threadIdx.x;
    int node = gid >> 5;
    int lane = gid & 31;
    if (node >= NN) return;
    int beg = row_ptr[node], end = row_ptr[node + 1];
    float acc = h_s[(size_t)node * 32 + lane];  // self loop
    for (int j0 = beg; j0 < end; j0 += 32) {
        int idx = j0 + lane;
        int myc = (idx < end) ? col[idx] : 0;
        int m = end - j0;
        if (m > 32) m = 32;
        for (int t = 0; t < m; ++t) {
            int c = __shfl(myc, t, 32);
            acc += h_s[(size_t)c * 32 + lane];
        }
    }
    float di = deg_inv[node];
    float v;
    if (MODE == 0) v = di * di * acc + di * b[lane];
    else           v = di * acc;
    out[(size_t)node * 32 + lane] = v;
}

// ---------------- pooling over F=32: segment sum + count, run-length pre-reduced ----------------
__global__ void pool_kernel(const float* __restrict__ h, const int* __restrict__ batch,
                            float* __restrict__ gsum, float* __restrict__ gcnt, int N) {
    int t = blockIdx.x * blockDim.x + threadIdx.x;
    int chunk = t / 32;
    int f = t % 32;
    int n0 = chunk * 16;
    if (n0 >= N) return;
    int n1 = min(n0 + 16, N);
    int cur = batch[n0];
    float acc = 0.f, ccnt = 0.f;
    for (int n = n0; n < n1; ++n) {
        int b = batch[n];
        if (b != cur) {
            unsafeAtomicAdd(&gsum[cur * 32 + f], acc);
            if (f == 0) unsafeAtomicAdd(&gcnt[cur], ccnt);
            acc = 0.f; ccnt = 0.f; cur = b;
        }
        acc += h[(size_t)n * 32 + f];
        ccnt += 1.f;
    }
    unsafeAtomicAdd(&gsum[cur * 32 + f], acc);
    if (f == 0) unsafeAtomicAdd(&gcnt[cur], ccnt);
}

// ---------------- head: W2+b2 -> fc1+relu -> batchnorm -> fc2 -> softplus ----------------
__global__ __launch_bounds__(256) void head_kernel(const float* __restrict__ gsum,
                                                   const float* __restrict__ gcnt,
                                                   const float* __restrict__ W2,
                                                   const float* __restrict__ b2,
                                                   const float* __restrict__ fcW1,
                                                   const float* __restrict__ fcb1,
                                                   const float* __restrict__ gamma,
                                                   const float* __restrict__ beta,
                                                   const float* __restrict__ fcW2,
                                                   const float* __restrict__ fcb2,
                                                   float* __restrict__ out) {
    __shared__ float zs[NG][33];
    __shared__ float mu[32], rstd[32];
    int g = threadIdx.x;
    float p32[32];
    float c = fmaxf(gcnt[g], 1.0f);
    float inv = 1.0f / c;
#pragma unroll
    for (int k = 0; k < 32; ++k) p32[k] = gsum[g * 32 + k] * inv;
    float p64[64];
#pragma unroll
    for (int j = 0; j < 64; ++j) {
        float acc = b2[j];
#pragma unroll
        for (int k = 0; k < 32; ++k) acc += p32[k] * W2[k * 64 + j];
        p64[j] = acc;
    }
    for (int ch = 0; ch < 32; ++ch) {
        float acc = fcb1[ch];
#pragma unroll
        for (int j = 0; j < 64; ++j) acc += p64[j] * fcW1[j * 32 + ch];
        zs[g][ch] = fmaxf(acc, 0.f);
    }
    __syncthreads();
    if (g < 32) {
        float s = 0.f;
        for (int i = 0; i < NG; ++i) s += zs[i][g];
        float m = s / NG;
        float v = 0.f;
        for (int i = 0; i < NG; ++i) { float d = zs[i][g] - m; v += d * d; }
        v /= NG;
        mu[g] = m;
        rstd[g] = rsqrtf(v + 1e-5f);
    }
    __syncthreads();
    float acc = fcb2[0];
    for (int ch = 0; ch < 32; ++ch) {
        float zn = (zs[g][ch] - mu[ch]) * rstd[ch] * gamma[ch] + beta[ch];
        acc += zn * fcW2[ch];
    }
    out[g] = fmaxf(acc, 0.f) + log1pf(expf(-fabsf(acc)));
}

extern "C" void kernel_launch(void* const* d_in, const int* in_sizes, int n_in,
                              void* d_out, int out_size, void* d_ws, size_t ws_size,
                              hipStream_t stream) {
    const float* x     = (const float*)d_in[0];
    const int*   ei    = (const int*)d_in[1];
    const int*   batch = (const int*)d_in[2];
    const float* W1    = (const float*)d_in[3];
    const float* b1    = (const float*)d_in[4];
    const float* W2    = (const float*)d_in[5];
    const float* b2    = (const float*)d_in[6];
    const float* fcW1  = (const float*)d_in[7];
    const float* fcb1  = (const float*)d_in[8];
    const float* gamma = (const float*)d_in[9];
    const float* beta  = (const float*)d_in[10];
    const float* fcW2  = (const float*)d_in[11];
    const float* fcb2  = (const float*)d_in[12];
    float* out = (float*)d_out;

    // workspace layout (all chunks 16B aligned)
    char* p = (char*)d_ws;
    int*   cnt     = (int*)p;        p += (size_t)NN * 4;
    float* deg_inv = (float*)p;      p += (size_t)NN * 4;
    int*   row_ptr = (int*)p;        p += (size_t)(NN + 8) * 4;
    int*   part    = (int*)p;        p += (size_t)NN * 4;
    int*   bsum    = (int*)p;        p += 128 * 4;
    int*   bsumex  = (int*)p;        p += 128 * 4;
    int*   rank    = (int*)p;        p += (size_t)NE * 4;
    int*   col     = (int*)p;        p += (size_t)NE * 4;
    float* h1s     = (float*)p;      p += (size_t)NN * 32 * 4;
    float* t1      = (float*)p;      p += (size_t)NN * 32 * 4;
    float* agg2    = (float*)p;      p += (size_t)NN * 32 * 4;
    float* gsum    = (float*)p;      p += (size_t)NG * 32 * 4;
    float* gcnt    = (float*)p;      p += (size_t)NG * 4;

    const int* srcv = ei;
    const int* dstv = ei + NE;

    hipMemsetAsync(cnt, 0, NN * sizeof(int), stream);
    hipMemsetAsync(gsum, 0, (NG * 32 + NG) * sizeof(float), stream);

    // CSR build (rank trick: no atomics in fill)
    hist_rank_kernel<<<(NE / 4 + 255) / 256, 256, 0, stream>>>(dstv, cnt, rank, NE / 4);
    scan1_kernel<<<NB_SCAN, 256, 0, stream>>>(cnt, part, bsum, deg_inv);
    scan2_kernel<<<1, 128, 0, stream>>>(bsum, bsumex);
    scan3_kernel<<<NB_SCAN, 256, 0, stream>>>(part, bsumex, row_ptr);
    fill_kernel<<<(NE / 4 + 255) / 256, 256, 0, stream>>>(srcv, dstv, rank, row_ptr, col, NE / 4);

    // layer 1: h1s = (x@W1)*deg_inv ; t1 = deg_inv^2*(h1s[d]+sum h1s[col]) + deg_inv*b1
    gemm_x_w1<<<(NN + 7) / 8, 256, 0, stream>>>(x, W1, deg_inv, h1s, NN);
    conv32_kernel<0><<<((size_t)NN * 32 + 255) / 256, 256, 0, stream>>>(row_ptr, col, h1s, deg_inv, b1, t1);

    // layer 2 aggregation only (GEMM with W2 deferred to head): agg2 = deg_inv*(t1[d]+sum t1[col])
    conv32_kernel<1><<<((size_t)NN * 32 + 255) / 256, 256, 0, stream>>>(row_ptr, col, t1, deg_inv, b1, agg2);

    // pooling (F=32) + head
    pool_kernel<<<(((NN + 15) / 16) * 32 + 255) / 256, 256, 0, stream>>>(agg2, batch, gsum, gcnt, NN);
    head_kernel<<<1, 256, 0, stream>>>(gsum, gcnt, W2, b2, fcW1, fcb1, gamma, beta, fcW2, fcb2, out);
}

// Round 4
// 402.743 us; speedup vs baseline: 1.4259x; 1.4259x over previous
//
#include <hip/hip_runtime.h>

#define NN 100000
#define NE 1600000
#define NG 256
#define SCAN_CHUNK 1024
#define NB_SCAN ((NN + SCAN_CHUNK - 1) / SCAN_CHUNK)  // 98

// ---------------- degree histogram + edge rank (int4, 4 edges/thread) ----------------
__global__ void hist_rank_kernel(const int* __restrict__ dst, int* __restrict__ cnt,
                                 int* __restrict__ rank, int E4) {
    int t = blockIdx.x * blockDim.x + threadIdx.x;
    if (t >= E4) return;
    int4 d = ((const int4*)dst)[t];
    int4 r;
    r.x = atomicAdd(&cnt[d.x], 1);
    r.y = atomicAdd(&cnt[d.y], 1);
    r.z = atomicAdd(&cnt[d.z], 1);
    r.w = atomicAdd(&cnt[d.w], 1);
    ((int4*)rank)[t] = r;
}

// ---------------- exclusive scan (3 kernels); scan1 also emits deg_inv ----------------
__global__ __launch_bounds__(256) void scan1_kernel(const int* __restrict__ cnt,
                                                    int* __restrict__ part,
                                                    int* __restrict__ bsum,
                                                    float* __restrict__ deg_inv) {
    __shared__ int ts[256];
    int tid = threadIdx.x;
    int base = blockIdx.x * SCAN_CHUNK + tid * 4;
    int v[4];
    int s = 0;
#pragma unroll
    for (int i = 0; i < 4; ++i) {
        v[i] = (base + i < NN) ? cnt[base + i] : 0;
        if (base + i < NN) deg_inv[base + i] = rsqrtf(1.0f + (float)v[i]);
        s += v[i];
    }
    ts[tid] = s;
    __syncthreads();
    for (int off = 1; off < 256; off <<= 1) {
        int t = (tid >= off) ? ts[tid - off] : 0;
        __syncthreads();
        ts[tid] += t;
        __syncthreads();
    }
    int run = ts[tid] - s;
#pragma unroll
    for (int i = 0; i < 4; ++i) {
        if (base + i < NN) part[base + i] = run;
        run += v[i];
    }
    if (tid == 255) bsum[blockIdx.x] = ts[255];
}

__global__ __launch_bounds__(128) void scan2_kernel(const int* __restrict__ bsum,
                                                    int* __restrict__ bsumex) {
    __shared__ int ts[128];
    int tid = threadIdx.x;
    int v = (tid < NB_SCAN) ? bsum[tid] : 0;
    ts[tid] = v;
    __syncthreads();
    for (int off = 1; off < 128; off <<= 1) {
        int t = (tid >= off) ? ts[tid - off] : 0;
        __syncthreads();
        ts[tid] += t;
        __syncthreads();
    }
    bsumex[tid] = ts[tid] - v;
}

__global__ __launch_bounds__(256) void scan3_kernel(const int* __restrict__ part,
                                                    const int* __restrict__ bsumex,
                                                    int* __restrict__ row_ptr) {
    int tid = threadIdx.x;
    int base = blockIdx.x * SCAN_CHUNK + tid * 4;
    int add = bsumex[blockIdx.x];
#pragma unroll
    for (int i = 0; i < 4; ++i) {
        int idx = base + i;
        if (idx < NN) row_ptr[idx] = part[idx] + add;
    }
    if (blockIdx.x == 0 && tid == 0) row_ptr[NN] = NE;
}

// ---------------- CSR fill: atomic-free scatter (4 edges/thread) ----------------
__global__ void fill_kernel(const int* __restrict__ src, const int* __restrict__ dst,
                            const int* __restrict__ rank, const int* __restrict__ row_ptr,
                            int* __restrict__ col, int E4) {
    int t = blockIdx.x * blockDim.x + threadIdx.x;
    if (t >= E4) return;
    int4 d = ((const int4*)dst)[t];
    int4 s = ((const int4*)src)[t];
    int4 r = ((const int4*)rank)[t];
    col[row_ptr[d.x] + r.x] = s.x;
    col[row_ptr[d.y] + r.y] = s.y;
    col[row_ptr[d.z] + r.z] = s.z;
    col[row_ptr[d.w] + r.w] = s.w;
}

// ---------------- GEMM1: [N,128] @ [128,32], epilogue scale by deg_inv ----------------
__global__ __launch_bounds__(256) void gemm_x_w1(const float* __restrict__ x,
                                                 const float* __restrict__ W,
                                                 const float* __restrict__ deg_inv,
                                                 float* __restrict__ h, int N) {
    __shared__ float wsh[128 * 32];
    __shared__ float xs[8][128];
    int tid = threadIdx.x;
    for (int i = tid; i < 128 * 32 / 4; i += 256)
        ((float4*)wsh)[i] = ((const float4*)W)[i];
    int row0 = blockIdx.x * 8;
    {
        int r = tid / 32, c4 = tid % 32;
        int row = row0 + r;
        float4 v = make_float4(0.f, 0.f, 0.f, 0.f);
        if (row < N) v = ((const float4*)x)[row * 32 + c4];
        ((float4*)xs[r])[c4] = v;
    }
    __syncthreads();
    int r = tid / 32, c = tid % 32;
    int row = row0 + r;
    float acc = 0.f;
#pragma unroll 8
    for (int k = 0; k < 128; ++k)
        acc += xs[r][k] * wsh[k * 32 + c];
    if (row < N) h[row * 32 + c] = acc * deg_inv[row];
}

// ---------------- gather conv F=32, one node per 32 lanes ----------------
// MODE 0 (layer1, fused rescale for layer2):  out[d] = di^2*acc + di*b[lane]
// MODE 1 (layer2 aggregation only):           out[d] = di*acc
template <int MODE>
__global__ __launch_bounds__(256) void conv32_kernel(const int* __restrict__ row_ptr,
                                                     const int* __restrict__ col,
                                                     const float* __restrict__ h_s,
                                                     const float* __restrict__ deg_inv,
                                                     const float* __restrict__ b,
                                                     float* __restrict__ out) {
    int gid = blockIdx.x * blockDim.x + threadIdx.x;
    int node = gid >> 5;
    int lane = gid & 31;
    if (node >= NN) return;
    int beg = row_ptr[node], end = row_ptr[node + 1];
    float acc = h_s[(size_t)node * 32 + lane];  // self loop
    for (int j0 = beg; j0 < end; j0 += 32) {
        int idx = j0 + lane;
        int myc = (idx < end) ? col[idx] : 0;
        int m = end - j0;
        if (m > 32) m = 32;
        for (int t = 0; t < m; ++t) {
            int c = __shfl(myc, t, 32);
            acc += h_s[(size_t)c * 32 + lane];
        }
    }
    float di = deg_inv[node];
    float v;
    if (MODE == 0) v = di * di * acc + di * b[lane];
    else           v = di * acc;
    out[(size_t)node * 32 + lane] = v;
}

// ---------------- pooling over F=32 ----------------
__global__ void pool_kernel(const float* __restrict__ h, const int* __restrict__ batch,
                            float* __restrict__ gsum, float* __restrict__ gcnt, int N) {
    int t = blockIdx.x * blockDim.x + threadIdx.x;
    int chunk = t / 32;
    int f = t % 32;
    int n0 = chunk * 16;
    if (n0 >= N) return;
    int n1 = min(n0 + 16, N);
    int cur = batch[n0];
    float acc = 0.f, ccnt = 0.f;
    for (int n = n0; n < n1; ++n) {
        int b = batch[n];
        if (b != cur) {
            unsafeAtomicAdd(&gsum[cur * 32 + f], acc);
            if (f == 0) unsafeAtomicAdd(&gcnt[cur], ccnt);
            acc = 0.f; ccnt = 0.f; cur = b;
        }
        acc += h[(size_t)n * 32 + f];
        ccnt += 1.f;
    }
    unsafeAtomicAdd(&gsum[cur * 32 + f], acc);
    if (f == 0) unsafeAtomicAdd(&gcnt[cur], ccnt);
}

// ---------------- fold small GEMMs: Wc = W2@fcW1 [32,32], bc = b2@fcW1+fcb1 ----------------
__global__ __launch_bounds__(256) void wc_kernel(const float* __restrict__ W2,
                                                 const float* __restrict__ b2,
                                                 const float* __restrict__ fcW1,
                                                 const float* __restrict__ fcb1,
                                                 float* __restrict__ Wc,
                                                 float* __restrict__ bc) {
    int t = threadIdx.x;
    for (int idx = t; idx < 32 * 32; idx += 256) {
        int k = idx / 32, ch = idx % 32;
        float acc = 0.f;
#pragma unroll
        for (int j = 0; j < 64; ++j) acc += W2[k * 64 + j] * fcW1[j * 32 + ch];
        Wc[idx] = acc;
    }
    if (t < 32) {
        float acc = fcb1[t];
#pragma unroll
        for (int j = 0; j < 64; ++j) acc += b2[j] * fcW1[j * 32 + t];
        bc[t] = acc;
    }
}

// ---------------- head: z=relu(p32@Wc+bc) -> batchnorm -> fc2 -> softplus ----------------
__global__ __launch_bounds__(256) void head_kernel(const float* __restrict__ gsum,
                                                   const float* __restrict__ gcnt,
                                                   const float* __restrict__ Wc,
                                                   const float* __restrict__ bc,
                                                   const float* __restrict__ gamma,
                                                   const float* __restrict__ beta,
                                                   const float* __restrict__ fcW2,
                                                   const float* __restrict__ fcb2,
                                                   float* __restrict__ out) {
    __shared__ float zs[NG][33];
    __shared__ float wcs[32 * 32];
    __shared__ float bcs[32];
    __shared__ float part1[8][32];
    __shared__ float part2[8][32];
    __shared__ float mu[32], rstd[32];
    int g = threadIdx.x;

    // stage Wc/bc into LDS
    for (int i = g; i < 32 * 32; i += 256) wcs[i] = Wc[i];
    if (g < 32) bcs[g] = bc[g];
    __syncthreads();

    // phase 1: per-graph z = relu(p32 @ Wc + bc)
    float p32[32];
    float inv = 1.0f / fmaxf(gcnt[g], 1.0f);
    {
        const float4* gs4 = (const float4*)(gsum + g * 32);
#pragma unroll
        for (int q = 0; q < 8; ++q) {
            float4 v = gs4[q];
            p32[q * 4 + 0] = v.x * inv;
            p32[q * 4 + 1] = v.y * inv;
            p32[q * 4 + 2] = v.z * inv;
            p32[q * 4 + 3] = v.w * inv;
        }
    }
#pragma unroll 4
    for (int ch = 0; ch < 32; ++ch) {
        float acc = bcs[ch];
#pragma unroll
        for (int k = 0; k < 32; ++k) acc += p32[k] * wcs[k * 32 + ch];
        zs[g][ch] = fmaxf(acc, 0.f);
    }
    __syncthreads();

    // phase 2: BN stats, parallel partials (8 segments x 32 channels)
    {
        int ch = g & 31, seg = g >> 5;
        float s = 0.f, sq = 0.f;
#pragma unroll
        for (int i = 0; i < 32; ++i) {
            float v = zs[seg * 32 + i][ch];
            s += v;
            sq += v * v;
        }
        part1[seg][ch] = s;
        part2[seg][ch] = sq;
    }
    __syncthreads();
    if (g < 32) {
        float s = 0.f, sq = 0.f;
#pragma unroll
        for (int i = 0; i < 8; ++i) { s += part1[i][g]; sq += part2[i][g]; }
        float m = s / NG;
        float v = sq / NG - m * m;
        mu[g] = m;
        rstd[g] = rsqrtf(fmaxf(v, 0.f) + 1e-5f);
    }
    __syncthreads();

    // phase 3: fc2 + softplus
    float acc = fcb2[0];
#pragma unroll 4
    for (int ch = 0; ch < 32; ++ch) {
        float zn = (zs[g][ch] - mu[ch]) * rstd[ch] * gamma[ch] + beta[ch];
        acc += zn * fcW2[ch];
    }
    out[g] = fmaxf(acc, 0.f) + log1pf(expf(-fabsf(acc)));
}

extern "C" void kernel_launch(void* const* d_in, const int* in_sizes, int n_in,
                              void* d_out, int out_size, void* d_ws, size_t ws_size,
                              hipStream_t stream) {
    const float* x     = (const float*)d_in[0];
    const int*   ei    = (const int*)d_in[1];
    const int*   batch = (const int*)d_in[2];
    const float* W1    = (const float*)d_in[3];
    const float* b1    = (const float*)d_in[4];
    const float* W2    = (const float*)d_in[5];
    const float* b2    = (const float*)d_in[6];
    const float* fcW1  = (const float*)d_in[7];
    const float* fcb1  = (const float*)d_in[8];
    const float* gamma = (const float*)d_in[9];
    const float* beta  = (const float*)d_in[10];
    const float* fcW2  = (const float*)d_in[11];
    const float* fcb2  = (const float*)d_in[12];
    float* out = (float*)d_out;

    // workspace layout (all chunks 16B aligned)
    char* p = (char*)d_ws;
    int*   cnt     = (int*)p;        p += (size_t)NN * 4;
    float* deg_inv = (float*)p;      p += (size_t)NN * 4;
    int*   row_ptr = (int*)p;        p += (size_t)(NN + 8) * 4;
    int*   part    = (int*)p;        p += (size_t)NN * 4;
    int*   bsum    = (int*)p;        p += 128 * 4;
    int*   bsumex  = (int*)p;        p += 128 * 4;
    int*   rank    = (int*)p;        p += (size_t)NE * 4;
    int*   col     = (int*)p;        p += (size_t)NE * 4;
    float* h1s     = (float*)p;      p += (size_t)NN * 32 * 4;
    float* t1      = (float*)p;      p += (size_t)NN * 32 * 4;
    float* agg2    = (float*)p;      p += (size_t)NN * 32 * 4;
    float* gsum    = (float*)p;      p += (size_t)NG * 32 * 4;
    float* gcnt    = (float*)p;      p += (size_t)NG * 4;  // NG floats (16B-mult)
    float* Wc      = (float*)p;      p += 32 * 32 * 4;
    float* bc      = (float*)p;      p += 32 * 4;

    const int* srcv = ei;
    const int* dstv = ei + NE;

    hipMemsetAsync(cnt, 0, NN * sizeof(int), stream);
    hipMemsetAsync(gsum, 0, (NG * 32 + NG) * sizeof(float), stream);

    // CSR build (rank trick: no atomics in fill)
    hist_rank_kernel<<<(NE / 4 + 255) / 256, 256, 0, stream>>>(dstv, cnt, rank, NE / 4);
    scan1_kernel<<<NB_SCAN, 256, 0, stream>>>(cnt, part, bsum, deg_inv);
    scan2_kernel<<<1, 128, 0, stream>>>(bsum, bsumex);
    scan3_kernel<<<NB_SCAN, 256, 0, stream>>>(part, bsumex, row_ptr);
    fill_kernel<<<(NE / 4 + 255) / 256, 256, 0, stream>>>(srcv, dstv, rank, row_ptr, col, NE / 4);

    // small-weight fold (independent of CSR)
    wc_kernel<<<1, 256, 0, stream>>>(W2, b2, fcW1, fcb1, Wc, bc);

    // layer 1
    gemm_x_w1<<<(NN + 7) / 8, 256, 0, stream>>>(x, W1, deg_inv, h1s, NN);
    conv32_kernel<0><<<((size_t)NN * 32 + 255) / 256, 256, 0, stream>>>(row_ptr, col, h1s, deg_inv, b1, t1);

    // layer 2 aggregation (W2 folded into head)
    conv32_kernel<1><<<((size_t)NN * 32 + 255) / 256, 256, 0, stream>>>(row_ptr, col, t1, deg_inv, b1, agg2);

    // pooling (F=32) + head
    pool_kernel<<<(((NN + 15) / 16) * 32 + 255) / 256, 256, 0, stream>>>(agg2, batch, gsum, gcnt, NN);
    head_kernel<<<1, 256, 0, stream>>>(gsum, gcnt, Wc, bc, gamma, beta, fcW2, fcb2, out);
}

// Round 6
// 357.737 us; speedup vs baseline: 1.6053x; 1.1258x over previous
//
#include <hip/hip_runtime.h>

#define NN 100000
#define NE 1600000
#define NG 256

#define BSH 7                 // bucket = dst >> 7  (128 nodes/bucket)
#define NPB 128               // nodes per bucket
#define NBKT ((NN + NPB - 1) / NPB)   // 782
#define TILE 4096
#define NB_P1 ((NE + TILE - 1) / TILE) // 391

// ---------------- pass 0: count edges per coarse bucket ----------------
__global__ __launch_bounds__(256) void count_kernel(const int* __restrict__ dst,
                                                    int* __restrict__ bkt_cnt) {
    __shared__ int hist[NBKT];
    int tid = threadIdx.x;
    int e0 = blockIdx.x * TILE;
    int e1 = min(e0 + TILE, NE);
    for (int i = tid; i < NBKT; i += 256) hist[i] = 0;
    __syncthreads();
    for (int e = e0 + tid; e < e1; e += 256)
        atomicAdd(&hist[dst[e] >> BSH], 1);
    __syncthreads();
    for (int i = tid; i < NBKT; i += 256) {
        int h = hist[i];
        if (h) atomicAdd(&bkt_cnt[i], h);  // non-returning
    }
}

// ---------------- scan bucket counts -> bases + reservation cursors ----------------
__global__ __launch_bounds__(1024) void scan_bkt_kernel(const int* __restrict__ bkt_cnt,
                                                        int* __restrict__ bkt_ptr,
                                                        int* __restrict__ bkt_cur) {
    __shared__ int ts[1024];
    int tid = threadIdx.x;
    int v = (tid < NBKT) ? bkt_cnt[tid] : 0;
    ts[tid] = v;
    __syncthreads();
    for (int off = 1; off < 1024; off <<= 1) {
        int t = (tid >= off) ? ts[tid - off] : 0;
        __syncthreads();
        ts[tid] += t;
        __syncthreads();
    }
    if (tid < NBKT) {
        int base = ts[tid] - v;
        bkt_ptr[tid] = base;
        bkt_cur[tid] = base;
    }
    if (tid == 0) bkt_ptr[NBKT] = NE;
}

// ---------------- pass 1: partition edges into bucket regions ----------------
__global__ __launch_bounds__(256) void part_kernel(const int* __restrict__ src,
                                                   const int* __restrict__ dst,
                                                   int* __restrict__ bkt_cur,
                                                   int2* __restrict__ epack) {
    __shared__ int hist[NBKT];
    __shared__ int cur[NBKT];
    int tid = threadIdx.x;
    int e0 = blockIdx.x * TILE;
    int e1 = min(e0 + TILE, NE);
    for (int i = tid; i < NBKT; i += 256) hist[i] = 0;
    __syncthreads();
    for (int e = e0 + tid; e < e1; e += 256)
        atomicAdd(&hist[dst[e] >> BSH], 1);
    __syncthreads();
    for (int i = tid; i < NBKT; i += 256) {
        int h = hist[i];
        cur[i] = h ? atomicAdd(&bkt_cur[i], h) : 0;  // GLOBAL base of this block's range
    }
    __syncthreads();
    for (int e = e0 + tid; e < e1; e += 256) {
        int d = dst[e];
        int pos = atomicAdd(&cur[d >> BSH], 1);      // globally unique, inside bucket region
        epack[pos] = make_int2(src[e], d);
    }
}

// ---------------- pass 2: per-bucket fine CSR build (LDS only) ----------------
__global__ __launch_bounds__(256) void build_kernel(const int2* __restrict__ epack,
                                                    const int* __restrict__ bkt_ptr,
                                                    int* __restrict__ row_ptr,
                                                    int* __restrict__ col,
                                                    float* __restrict__ deg_inv) {
    __shared__ int cnt[NPB];
    __shared__ int ts[NPB];
    int b = blockIdx.x;
    int tid = threadIdx.x;
    int ebase = bkt_ptr[b], eend = bkt_ptr[b + 1];
    int nbase = b << BSH;
    if (tid < NPB) cnt[tid] = 0;
    __syncthreads();
    for (int e = ebase + tid; e < eend; e += 256)
        atomicAdd(&cnt[epack[e].y & (NPB - 1)], 1);
    __syncthreads();
    int v = (tid < NPB) ? cnt[tid] : 0;
    if (tid < NPB) ts[tid] = v;
    __syncthreads();
    for (int off = 1; off < NPB; off <<= 1) {
        int t = (tid >= off && tid < NPB) ? ts[tid - off] : 0;
        __syncthreads();
        if (tid < NPB) ts[tid] += t;
        __syncthreads();
    }
    if (tid < NPB) {
        int loff = ts[tid] - v;  // exclusive prefix within bucket
        int node = nbase + tid;
        if (node < NN) {
            row_ptr[node] = ebase + loff;
            deg_inv[node] = rsqrtf(1.0f + (float)v);
        }
        cnt[tid] = loff;  // reuse as cursor
    }
    if (b == 0 && tid == 0) row_ptr[NN] = NE;
    __syncthreads();
    for (int e = ebase + tid; e < eend; e += 256) {
        int2 sd = epack[e];
        int r = atomicAdd(&cnt[sd.y & (NPB - 1)], 1);
        col[ebase + r] = sd.x;
    }
}

// ---------------- GEMM1: [N,128] @ [128,32], epilogue scale by deg_inv ----------------
__global__ __launch_bounds__(256) void gemm_x_w1(const float* __restrict__ x,
                                                 const float* __restrict__ W,
                                                 const float* __restrict__ deg_inv,
                                                 float* __restrict__ h, int N) {
    __shared__ float wsh[128 * 32];
    __shared__ float xs[8][128];
    int tid = threadIdx.x;
    for (int i = tid; i < 128 * 32 / 4; i += 256)
        ((float4*)wsh)[i] = ((const float4*)W)[i];
    int row0 = blockIdx.x * 8;
    {
        int r = tid / 32, c4 = tid % 32;
        int row = row0 + r;
        float4 v = make_float4(0.f, 0.f, 0.f, 0.f);
        if (row < N) v = ((const float4*)x)[row * 32 + c4];
        ((float4*)xs[r])[c4] = v;
    }
    __syncthreads();
    int r = tid / 32, c = tid % 32;
    int row = row0 + r;
    float acc = 0.f;
#pragma unroll 8
    for (int k = 0; k < 128; ++k)
        acc += xs[r][k] * wsh[k * 32 + c];
    if (row < N) h[row * 32 + c] = acc * deg_inv[row];
}

// ---------------- gather conv F=32, one node per 32 lanes ----------------
// MODE 0 (layer1, fused rescale for layer2):  out[d] = di^2*acc + di*b[lane]
// MODE 1 (layer2 aggregation only):           out[d] = di*acc
template <int MODE>
__global__ __launch_bounds__(256) void conv32_kernel(const int* __restrict__ row_ptr,
                                                     const int* __restrict__ col,
                                                     const float* __restrict__ h_s,
                                                     const float* __restrict__ deg_inv,
                                                     const float* __restrict__ b,
                                                     float* __restrict__ out) {
    int gid = blockIdx.x * blockDim.x + threadIdx.x;
    int node = gid >> 5;
    int lane = gid & 31;
    if (node >= NN) return;
    int beg = row_ptr[node], end = row_ptr[node + 1];
    float acc = h_s[(size_t)node * 32 + lane];  // self loop
    for (int j0 = beg; j0 < end; j0 += 32) {
        int idx = j0 + lane;
        int myc = (idx < end) ? col[idx] : 0;
        int m = end - j0;
        if (m > 32) m = 32;
        for (int t = 0; t < m; ++t) {
            int c = __shfl(myc, t, 32);
            acc += h_s[(size_t)c * 32 + lane];
        }
    }
    float di = deg_inv[node];
    float v;
    if (MODE == 0) v = di * di * acc + di * b[lane];
    else           v = di * acc;
    out[(size_t)node * 32 + lane] = v;
}

// ---------------- pooling over F=32 ----------------
__global__ void pool_kernel(const float* __restrict__ h, const int* __restrict__ batch,
                            float* __restrict__ gsum, float* __restrict__ gcnt, int N) {
    int t = blockIdx.x * blockDim.x + threadIdx.x;
    int chunk = t / 32;
    int f = t % 32;
    int n0 = chunk * 16;
    if (n0 >= N) return;
    int n1 = min(n0 + 16, N);
    int cur = batch[n0];
    float acc = 0.f, ccnt = 0.f;
    for (int n = n0; n < n1; ++n) {
        int b = batch[n];
        if (b != cur) {
            unsafeAtomicAdd(&gsum[cur * 32 + f], acc);
            if (f == 0) unsafeAtomicAdd(&gcnt[cur], ccnt);
            acc = 0.f; ccnt = 0.f; cur = b;
        }
        acc += h[(size_t)n * 32 + f];
        ccnt += 1.f;
    }
    unsafeAtomicAdd(&gsum[cur * 32 + f], acc);
    if (f == 0) unsafeAtomicAdd(&gcnt[cur], ccnt);
}

// ---------------- fold small GEMMs: Wc = W2@fcW1 [32,32], bc = b2@fcW1+fcb1 ----------------
__global__ __launch_bounds__(256) void wc_kernel(const float* __restrict__ W2,
                                                 const float* __restrict__ b2,
                                                 const float* __restrict__ fcW1,
                                                 const float* __restrict__ fcb1,
                                                 float* __restrict__ Wc,
                                                 float* __restrict__ bc) {
    int t = threadIdx.x;
    for (int idx = t; idx < 32 * 32; idx += 256) {
        int k = idx / 32, ch = idx % 32;
        float acc = 0.f;
#pragma unroll
        for (int j = 0; j < 64; ++j) acc += W2[k * 64 + j] * fcW1[j * 32 + ch];
        Wc[idx] = acc;
    }
    if (t < 32) {
        float acc = fcb1[t];
#pragma unroll
        for (int j = 0; j < 64; ++j) acc += b2[j] * fcW1[j * 32 + t];
        bc[t] = acc;
    }
}

// ---------------- head: z=relu(p32@Wc+bc) -> batchnorm -> fc2 -> softplus ----------------
__global__ __launch_bounds__(256) void head_kernel(const float* __restrict__ gsum,
                                                   const float* __restrict__ gcnt,
                                                   const float* __restrict__ Wc,
                                                   const float* __restrict__ bc,
                                                   const float* __restrict__ gamma,
                                                   const float* __restrict__ beta,
                                                   const float* __restrict__ fcW2,
                                                   const float* __restrict__ fcb2,
                                                   float* __restrict__ out) {
    __shared__ float zs[NG][33];
    __shared__ float wcs[32 * 32];
    __shared__ float bcs[32];
    __shared__ float part1[8][32];
    __shared__ float part2[8][32];
    __shared__ float mu[32], rstd[32];
    int g = threadIdx.x;

    for (int i = g; i < 32 * 32; i += 256) wcs[i] = Wc[i];
    if (g < 32) bcs[g] = bc[g];
    __syncthreads();

    float p32[32];
    float inv = 1.0f / fmaxf(gcnt[g], 1.0f);
    {
        const float4* gs4 = (const float4*)(gsum + g * 32);
#pragma unroll
        for (int q = 0; q < 8; ++q) {
            float4 v = gs4[q];
            p32[q * 4 + 0] = v.x * inv;
            p32[q * 4 + 1] = v.y * inv;
            p32[q * 4 + 2] = v.z * inv;
            p32[q * 4 + 3] = v.w * inv;
        }
    }
#pragma unroll 4
    for (int ch = 0; ch < 32; ++ch) {
        float acc = bcs[ch];
#pragma unroll
        for (int k = 0; k < 32; ++k) acc += p32[k] * wcs[k * 32 + ch];
        zs[g][ch] = fmaxf(acc, 0.f);
    }
    __syncthreads();

    {
        int ch = g & 31, seg = g >> 5;
        float s = 0.f, sq = 0.f;
#pragma unroll
        for (int i = 0; i < 32; ++i) {
            float v = zs[seg * 32 + i][ch];
            s += v;
            sq += v * v;
        }
        part1[seg][ch] = s;
        part2[seg][ch] = sq;
    }
    __syncthreads();
    if (g < 32) {
        float s = 0.f, sq = 0.f;
#pragma unroll
        for (int i = 0; i < 8; ++i) { s += part1[i][g]; sq += part2[i][g]; }
        float m = s / NG;
        float v = sq / NG - m * m;
        mu[g] = m;
        rstd[g] = rsqrtf(fmaxf(v, 0.f) + 1e-5f);
    }
    __syncthreads();

    float acc = fcb2[0];
#pragma unroll 4
    for (int ch = 0; ch < 32; ++ch) {
        float zn = (zs[g][ch] - mu[ch]) * rstd[ch] * gamma[ch] + beta[ch];
        acc += zn * fcW2[ch];
    }
    out[g] = fmaxf(acc, 0.f) + log1pf(expf(-fabsf(acc)));
}

extern "C" void kernel_launch(void* const* d_in, const int* in_sizes, int n_in,
                              void* d_out, int out_size, void* d_ws, size_t ws_size,
                              hipStream_t stream) {
    const float* x     = (const float*)d_in[0];
    const int*   ei    = (const int*)d_in[1];
    const int*   batch = (const int*)d_in[2];
    const float* W1    = (const float*)d_in[3];
    const float* b1    = (const float*)d_in[4];
    const float* W2    = (const float*)d_in[5];
    const float* b2    = (const float*)d_in[6];
    const float* fcW1  = (const float*)d_in[7];
    const float* fcb1  = (const float*)d_in[8];
    const float* gamma = (const float*)d_in[9];
    const float* beta  = (const float*)d_in[10];
    const float* fcW2  = (const float*)d_in[11];
    const float* fcb2  = (const float*)d_in[12];
    float* out = (float*)d_out;

    // workspace layout (all chunks 16B aligned)
    char* p = (char*)d_ws;
    int*   bkt_cnt = (int*)p;        p += 800 * 4;
    int*   bkt_ptr = (int*)p;        p += 800 * 4;
    int*   bkt_cur = (int*)p;        p += 800 * 4;
    float* deg_inv = (float*)p;      p += (size_t)NN * 4;
    int*   row_ptr = (int*)p;        p += (size_t)(NN + 8) * 4;
    int2*  epack   = (int2*)p;       p += (size_t)NE * 8;
    int*   col     = (int*)p;        p += (size_t)NE * 4;
    float* h1s     = (float*)p;      p += (size_t)NN * 32 * 4;
    float* t1      = (float*)p;      p += (size_t)NN * 32 * 4;
    float* agg2    = (float*)p;      p += (size_t)NN * 32 * 4;
    float* gsum    = (float*)p;      p += (size_t)NG * 32 * 4;
    float* gcnt    = (float*)p;      p += (size_t)NG * 4;
    float* Wc      = (float*)p;      p += 32 * 32 * 4;
    float* bc      = (float*)p;      p += 32 * 4;

    const int* srcv = ei;
    const int* dstv = ei + NE;

    hipMemsetAsync(bkt_cnt, 0, NBKT * sizeof(int), stream);
    hipMemsetAsync(gsum, 0, (NG * 32 + NG) * sizeof(float), stream);

    // CSR build: count -> scan (bases + cursors) -> partition -> per-bucket build
    count_kernel<<<NB_P1, 256, 0, stream>>>(dstv, bkt_cnt);
    scan_bkt_kernel<<<1, 1024, 0, stream>>>(bkt_cnt, bkt_ptr, bkt_cur);
    part_kernel<<<NB_P1, 256, 0, stream>>>(srcv, dstv, bkt_cur, epack);
    build_kernel<<<NBKT, 256, 0, stream>>>(epack, bkt_ptr, row_ptr, col, deg_inv);

    // small-weight fold
    wc_kernel<<<1, 256, 0, stream>>>(W2, b2, fcW1, fcb1, Wc, bc);

    // layer 1
    gemm_x_w1<<<(NN + 7) / 8, 256, 0, stream>>>(x, W1, deg_inv, h1s, NN);
    conv32_kernel<0><<<((size_t)NN * 32 + 255) / 256, 256, 0, stream>>>(row_ptr, col, h1s, deg_inv, b1, t1);

    // layer 2 aggregation (W2 folded into head)
    conv32_kernel<1><<<((size_t)NN * 32 + 255) / 256, 256, 0, stream>>>(row_ptr, col, t1, deg_inv, b1, agg2);

    // pooling (F=32) + head
    pool_kernel<<<(((NN + 15) / 16) * 32 + 255) / 256, 256, 0, stream>>>(agg2, batch, gsum, gcnt, NN);
    head_kernel<<<1, 256, 0, stream>>>(gsum, gcnt, Wc, bc, gamma, beta, fcW2, fcb2, out);
}

// Round 7
// 316.402 us; speedup vs baseline: 1.8150x; 1.1306x over previous
//
#include <hip/hip_runtime.h>

#define NN 100000
#define NE 1600000
#define NG 256

#define BSH 7                 // bucket = dst >> 7  (128 nodes/bucket)
#define NPB 128               // nodes per bucket
#define NBKT ((NN + NPB - 1) / NPB)   // 782
#define TILE 8192
#define NB_P1 ((NE + TILE - 1) / TILE) // 196

__device__ __forceinline__ unsigned short f2bf(float x) {
    unsigned int u = __float_as_uint(x);
    u += 0x7FFFu + ((u >> 16) & 1u);   // round-to-nearest-even
    return (unsigned short)(u >> 16);
}
__device__ __forceinline__ float2 bf2x2(unsigned int v) {
    float2 r;
    r.x = __uint_as_float(v << 16);
    r.y = __uint_as_float(v & 0xFFFF0000u);
    return r;
}

// ---------------- pass 0: count edges per coarse bucket ----------------
__global__ __launch_bounds__(256) void count_kernel(const int* __restrict__ dst,
                                                    int* __restrict__ bkt_cnt) {
    __shared__ int hist[NBKT];
    int tid = threadIdx.x;
    int e0 = blockIdx.x * TILE;
    int e1 = min(e0 + TILE, NE);
    for (int i = tid; i < NBKT; i += 256) hist[i] = 0;
    __syncthreads();
    for (int e = e0 + tid; e < e1; e += 256)
        atomicAdd(&hist[dst[e] >> BSH], 1);
    __syncthreads();
    for (int i = tid; i < NBKT; i += 256) {
        int h = hist[i];
        if (h) atomicAdd(&bkt_cnt[i], h);  // non-returning
    }
}

// ---------------- scan bucket counts -> bases + reservation cursors ----------------
__global__ __launch_bounds__(1024) void scan_bkt_kernel(const int* __restrict__ bkt_cnt,
                                                        int* __restrict__ bkt_ptr,
                                                        int* __restrict__ bkt_cur) {
    __shared__ int ts[1024];
    int tid = threadIdx.x;
    int v = (tid < NBKT) ? bkt_cnt[tid] : 0;
    ts[tid] = v;
    __syncthreads();
    for (int off = 1; off < 1024; off <<= 1) {
        int t = (tid >= off) ? ts[tid - off] : 0;
        __syncthreads();
        ts[tid] += t;
        __syncthreads();
    }
    if (tid < NBKT) {
        int base = ts[tid] - v;
        bkt_ptr[tid] = base;
        bkt_cur[tid] = base;
    }
    if (tid == 0) bkt_ptr[NBKT] = NE;
}

// ---------------- pass 1: partition edges (packed: src | local<<17) ----------------
__global__ __launch_bounds__(256) void part_kernel(const int* __restrict__ src,
                                                   const int* __restrict__ dst,
                                                   int* __restrict__ bkt_cur,
                                                   int* __restrict__ epack) {
    __shared__ int hist[NBKT];
    __shared__ int cur[NBKT];
    int tid = threadIdx.x;
    int e0 = blockIdx.x * TILE;
    int e1 = min(e0 + TILE, NE);
    for (int i = tid; i < NBKT; i += 256) hist[i] = 0;
    __syncthreads();
    for (int e = e0 + tid; e < e1; e += 256)
        atomicAdd(&hist[dst[e] >> BSH], 1);
    __syncthreads();
    for (int i = tid; i < NBKT; i += 256) {
        int h = hist[i];
        cur[i] = h ? atomicAdd(&bkt_cur[i], h) : 0;  // global base of this block's range
    }
    __syncthreads();
    for (int e = e0 + tid; e < e1; e += 256) {
        int d = dst[e];
        int pos = atomicAdd(&cur[d >> BSH], 1);
        epack[pos] = src[e] | ((d & (NPB - 1)) << 17);
    }
}

// ---------------- pass 2: per-bucket fine CSR build (LDS only) ----------------
__global__ __launch_bounds__(256) void build_kernel(const int* __restrict__ epack,
                                                    const int* __restrict__ bkt_ptr,
                                                    int* __restrict__ row_ptr,
                                                    int* __restrict__ col,
                                                    float* __restrict__ deg_inv) {
    __shared__ int cnt[NPB];
    __shared__ int ts[NPB];
    int b = blockIdx.x;
    int tid = threadIdx.x;
    int ebase = bkt_ptr[b], eend = bkt_ptr[b + 1];
    int nbase = b << BSH;
    if (tid < NPB) cnt[tid] = 0;
    __syncthreads();
    for (int e = ebase + tid; e < eend; e += 256)
        atomicAdd(&cnt[epack[e] >> 17], 1);
    __syncthreads();
    int v = (tid < NPB) ? cnt[tid] : 0;
    if (tid < NPB) ts[tid] = v;
    __syncthreads();
    for (int off = 1; off < NPB; off <<= 1) {
        int t = (tid >= off && tid < NPB) ? ts[tid - off] : 0;
        __syncthreads();
        if (tid < NPB) ts[tid] += t;
        __syncthreads();
    }
    if (tid < NPB) {
        int loff = ts[tid] - v;
        int node = nbase + tid;
        if (node < NN) {
            row_ptr[node] = ebase + loff;
            deg_inv[node] = rsqrtf(1.0f + (float)v);
        }
        cnt[tid] = loff;  // reuse as cursor
    }
    if (b == 0 && tid == 0) row_ptr[NN] = NE;
    __syncthreads();
    for (int e = ebase + tid; e < eend; e += 256) {
        int rec = epack[e];
        int r = atomicAdd(&cnt[rec >> 17], 1);
        col[ebase + r] = rec & 0x1FFFF;
    }
}

// ---------------- GEMM1: [N,128]@[128,32], epilogue scale + bf16 pack ----------------
__global__ __launch_bounds__(256) void gemm_x_w1(const float* __restrict__ x,
                                                 const float* __restrict__ W,
                                                 const float* __restrict__ deg_inv,
                                                 unsigned short* __restrict__ h, int N) {
    __shared__ float wsh[128 * 32];
    __shared__ float xs[8][128];
    int tid = threadIdx.x;
    for (int i = tid; i < 128 * 32 / 4; i += 256)
        ((float4*)wsh)[i] = ((const float4*)W)[i];
    int row0 = blockIdx.x * 8;
    {
        int r = tid / 32, c4 = tid % 32;
        int row = row0 + r;
        float4 v = make_float4(0.f, 0.f, 0.f, 0.f);
        if (row < N) v = ((const float4*)x)[row * 32 + c4];
        ((float4*)xs[r])[c4] = v;
    }
    __syncthreads();
    int r = tid / 32, c = tid % 32;
    int row = row0 + r;
    float acc = 0.f;
#pragma unroll 8
    for (int k = 0; k < 128; ++k)
        acc += xs[r][k] * wsh[k * 32 + c];
    if (row < N) h[(size_t)row * 32 + c] = f2bf(acc * deg_inv[row]);
}

// ---------------- gather conv F=32 (bf16), one node per 16 lanes ----------------
// h viewed as uint[node*16 + L] (L owns feats 2L,2L+1)
// MODE 0: out_bf[node] = bf16( di^2*acc + di*b )   (feeds conv2)
// MODE 1: out_f32[node] = di*acc                   (feeds pooling)
template <int MODE>
__global__ __launch_bounds__(256) void conv_bf_kernel(const int* __restrict__ row_ptr,
                                                      const int* __restrict__ col,
                                                      const unsigned int* __restrict__ h,
                                                      const float* __restrict__ deg_inv,
                                                      const float* __restrict__ b,
                                                      unsigned int* __restrict__ out_bf,
                                                      float2* __restrict__ out_f32) {
    int gid = blockIdx.x * blockDim.x + threadIdx.x;
    int node = gid >> 4;
    int L = gid & 15;
    if (node >= NN) return;
    int beg = row_ptr[node], end = row_ptr[node + 1];
    float2 acc = bf2x2(h[node * 16 + L]);  // self loop
    for (int j0 = beg; j0 < end; j0 += 16) {
        int idx = j0 + L;
        int myc = (idx < end) ? col[idx] : 0;
        int m = end - j0;
        if (m > 16) m = 16;
        for (int t = 0; t < m; ++t) {
            int c = __shfl(myc, t, 16);
            float2 v = bf2x2(h[c * 16 + L]);
            acc.x += v.x;
            acc.y += v.y;
        }
    }
    float di = deg_inv[node];
    if (MODE == 0) {
        float ox = di * di * acc.x + di * b[2 * L];
        float oy = di * di * acc.y + di * b[2 * L + 1];
        out_bf[node * 16 + L] = (unsigned int)f2bf(ox) | ((unsigned int)f2bf(oy) << 16);
    } else {
        out_f32[node * 16 + L] = make_float2(di * acc.x, di * acc.y);
    }
}

// ---------------- pooling over F=32 (fp32 input) ----------------
__global__ void pool_kernel(const float* __restrict__ h, const int* __restrict__ batch,
                            float* __restrict__ gsum, float* __restrict__ gcnt, int N) {
    int t = blockIdx.x * blockDim.x + threadIdx.x;
    int chunk = t / 32;
    int f = t % 32;
    int n0 = chunk * 16;
    if (n0 >= N) return;
    int n1 = min(n0 + 16, N);
    int cur = batch[n0];
    float acc = 0.f, ccnt = 0.f;
    for (int n = n0; n < n1; ++n) {
        int b = batch[n];
        if (b != cur) {
            unsafeAtomicAdd(&gsum[cur * 32 + f], acc);
            if (f == 0) unsafeAtomicAdd(&gcnt[cur], ccnt);
            acc = 0.f; ccnt = 0.f; cur = b;
        }
        acc += h[(size_t)n * 32 + f];
        ccnt += 1.f;
    }
    unsafeAtomicAdd(&gsum[cur * 32 + f], acc);
    if (f == 0) unsafeAtomicAdd(&gcnt[cur], ccnt);
}

// ---------------- fold small GEMMs: Wc = W2@fcW1 [32,32], bc = b2@fcW1+fcb1 ----------------
__global__ __launch_bounds__(256) void wc_kernel(const float* __restrict__ W2,
                                                 const float* __restrict__ b2,
                                                 const float* __restrict__ fcW1,
                                                 const float* __restrict__ fcb1,
                                                 float* __restrict__ Wc,
                                                 float* __restrict__ bc) {
    int t = threadIdx.x;
    for (int idx = t; idx < 32 * 32; idx += 256) {
        int k = idx / 32, ch = idx % 32;
        float acc = 0.f;
#pragma unroll
        for (int j = 0; j < 64; ++j) acc += W2[k * 64 + j] * fcW1[j * 32 + ch];
        Wc[idx] = acc;
    }
    if (t < 32) {
        float acc = fcb1[t];
#pragma unroll
        for (int j = 0; j < 64; ++j) acc += b2[j] * fcW1[j * 32 + t];
        bc[t] = acc;
    }
}

// ---------------- head: z=relu(p32@Wc+bc) -> batchnorm -> fc2 -> softplus ----------------
__global__ __launch_bounds__(256) void head_kernel(const float* __restrict__ gsum,
                                                   const float* __restrict__ gcnt,
                                                   const float* __restrict__ Wc,
                                                   const float* __restrict__ bc,
                                                   const float* __restrict__ gamma,
                                                   const float* __restrict__ beta,
                                                   const float* __restrict__ fcW2,
                                                   const float* __restrict__ fcb2,
                                                   float* __restrict__ out) {
    __shared__ float zs[NG][33];
    __shared__ float wcs[32 * 32];
    __shared__ float bcs[32];
    __shared__ float part1[8][32];
    __shared__ float part2[8][32];
    __shared__ float mu[32], rstd[32];
    int g = threadIdx.x;

    for (int i = g; i < 32 * 32; i += 256) wcs[i] = Wc[i];
    if (g < 32) bcs[g] = bc[g];
    __syncthreads();

    float p32[32];
    float inv = 1.0f / fmaxf(gcnt[g], 1.0f);
    {
        const float4* gs4 = (const float4*)(gsum + g * 32);
#pragma unroll
        for (int q = 0; q < 8; ++q) {
            float4 v = gs4[q];
            p32[q * 4 + 0] = v.x * inv;
            p32[q * 4 + 1] = v.y * inv;
            p32[q * 4 + 2] = v.z * inv;
            p32[q * 4 + 3] = v.w * inv;
        }
    }
#pragma unroll 4
    for (int ch = 0; ch < 32; ++ch) {
        float acc = bcs[ch];
#pragma unroll
        for (int k = 0; k < 32; ++k) acc += p32[k] * wcs[k * 32 + ch];
        zs[g][ch] = fmaxf(acc, 0.f);
    }
    __syncthreads();

    {
        int ch = g & 31, seg = g >> 5;
        float s = 0.f, sq = 0.f;
#pragma unroll
        for (int i = 0; i < 32; ++i) {
            float v = zs[seg * 32 + i][ch];
            s += v;
            sq += v * v;
        }
        part1[seg][ch] = s;
        part2[seg][ch] = sq;
    }
    __syncthreads();
    if (g < 32) {
        float s = 0.f, sq = 0.f;
#pragma unroll
        for (int i = 0; i < 8; ++i) { s += part1[i][g]; sq += part2[i][g]; }
        float m = s / NG;
        float v = sq / NG - m * m;
        mu[g] = m;
        rstd[g] = rsqrtf(fmaxf(v, 0.f) + 1e-5f);
    }
    __syncthreads();

    float acc = fcb2[0];
#pragma unroll 4
    for (int ch = 0; ch < 32; ++ch) {
        float zn = (zs[g][ch] - mu[ch]) * rstd[ch] * gamma[ch] + beta[ch];
        acc += zn * fcW2[ch];
    }
    out[g] = fmaxf(acc, 0.f) + log1pf(expf(-fabsf(acc)));
}

extern "C" void kernel_launch(void* const* d_in, const int* in_sizes, int n_in,
                              void* d_out, int out_size, void* d_ws, size_t ws_size,
                              hipStream_t stream) {
    const float* x     = (const float*)d_in[0];
    const int*   ei    = (const int*)d_in[1];
    const int*   batch = (const int*)d_in[2];
    const float* W1    = (const float*)d_in[3];
    const float* b1    = (const float*)d_in[4];
    const float* W2    = (const float*)d_in[5];
    const float* b2    = (const float*)d_in[6];
    const float* fcW1  = (const float*)d_in[7];
    const float* fcb1  = (const float*)d_in[8];
    const float* gamma = (const float*)d_in[9];
    const float* beta  = (const float*)d_in[10];
    const float* fcW2  = (const float*)d_in[11];
    const float* fcb2  = (const float*)d_in[12];
    float* out = (float*)d_out;

    // workspace layout (all chunks 16B aligned)
    char* p = (char*)d_ws;
    int*   bkt_cnt = (int*)p;        p += 800 * 4;
    int*   bkt_ptr = (int*)p;        p += 800 * 4;
    int*   bkt_cur = (int*)p;        p += 800 * 4;
    float* deg_inv = (float*)p;      p += (size_t)NN * 4;
    int*   row_ptr = (int*)p;        p += (size_t)(NN + 8) * 4;
    int*   epack   = (int*)p;        p += (size_t)NE * 4;
    int*   col     = (int*)p;        p += (size_t)NE * 4;
    unsigned short* h1s = (unsigned short*)p;  p += (size_t)NN * 32 * 2;  // bf16
    unsigned int*   t1  = (unsigned int*)p;    p += (size_t)NN * 16 * 4;  // bf16x2
    float* agg2    = (float*)p;      p += (size_t)NN * 32 * 4;
    float* gsum    = (float*)p;      p += (size_t)NG * 32 * 4;
    float* gcnt    = (float*)p;      p += (size_t)NG * 4;
    float* Wc      = (float*)p;      p += 32 * 32 * 4;
    float* bc      = (float*)p;      p += 32 * 4;

    const int* srcv = ei;
    const int* dstv = ei + NE;

    hipMemsetAsync(bkt_cnt, 0, NBKT * sizeof(int), stream);
    hipMemsetAsync(gsum, 0, (NG * 32 + NG) * sizeof(float), stream);

    // CSR build: count -> scan -> partition (packed) -> per-bucket build
    count_kernel<<<NB_P1, 256, 0, stream>>>(dstv, bkt_cnt);
    scan_bkt_kernel<<<1, 1024, 0, stream>>>(bkt_cnt, bkt_ptr, bkt_cur);
    part_kernel<<<NB_P1, 256, 0, stream>>>(srcv, dstv, bkt_cur, epack);
    build_kernel<<<NBKT, 256, 0, stream>>>(epack, bkt_ptr, row_ptr, col, deg_inv);

    // small-weight fold
    wc_kernel<<<1, 256, 0, stream>>>(W2, b2, fcW1, fcb1, Wc, bc);

    // layer 1: h1s(bf16) = (x@W1)*deg_inv ; t1(bf16) = di^2*agg + di*b1
    gemm_x_w1<<<(NN + 7) / 8, 256, 0, stream>>>(x, W1, deg_inv, h1s, NN);
    conv_bf_kernel<0><<<((size_t)NN * 16 + 255) / 256, 256, 0, stream>>>(
        row_ptr, col, (const unsigned int*)h1s, deg_inv, b1, t1, nullptr);

    // layer 2 aggregation (W2 folded into head): agg2(fp32) = di*agg
    conv_bf_kernel<1><<<((size_t)NN * 16 + 255) / 256, 256, 0, stream>>>(
        row_ptr, col, t1, deg_inv, b1, nullptr, (float2*)agg2);

    // pooling (F=32) + head
    pool_kernel<<<(((NN + 15) / 16) * 32 + 255) / 256, 256, 0, stream>>>(agg2, batch, gsum, gcnt, NN);
    head_kernel<<<1, 256, 0, stream>>>(gsum, gcnt, Wc, bc, gamma, beta, fcW2, fcb2, out);
}

// Round 8
// 295.271 us; speedup vs baseline: 1.9449x; 1.0716x over previous
//
#include <hip/hip_runtime.h>

#define NN 100000
#define NE 1600000
#define NG 256

#define BSH 7                 // bucket = dst >> 7  (128 nodes/bucket)
#define NPB 128               // nodes per bucket
#define NBKT ((NN + NPB - 1) / NPB)   // 782
#define TILE 8192
#define NB_P1 ((NE + TILE - 1) / TILE) // 196

__device__ __forceinline__ unsigned short f2bf(float x) {
    unsigned int u = __float_as_uint(x);
    u += 0x7FFFu + ((u >> 16) & 1u);   // round-to-nearest-even
    return (unsigned short)(u >> 16);
}
__device__ __forceinline__ float2 bf2x2(unsigned int v) {
    float2 r;
    r.x = __uint_as_float(v << 16);
    r.y = __uint_as_float(v & 0xFFFF0000u);
    return r;
}

// ---------------- pass 0: count edges per coarse bucket ----------------
__global__ __launch_bounds__(256) void count_kernel(const int* __restrict__ dst,
                                                    int* __restrict__ bkt_cnt) {
    __shared__ int hist[NBKT];
    int tid = threadIdx.x;
    int e0 = blockIdx.x * TILE;
    int e1 = min(e0 + TILE, NE);
    for (int i = tid; i < NBKT; i += 256) hist[i] = 0;
    __syncthreads();
    for (int e = e0 + tid; e < e1; e += 256)
        atomicAdd(&hist[dst[e] >> BSH], 1);
    __syncthreads();
    for (int i = tid; i < NBKT; i += 256) {
        int h = hist[i];
        if (h) atomicAdd(&bkt_cnt[i], h);  // non-returning
    }
}

// ---------------- scan bucket counts -> bases + reservation cursors ----------------
__global__ __launch_bounds__(1024) void scan_bkt_kernel(const int* __restrict__ bkt_cnt,
                                                        int* __restrict__ bkt_ptr,
                                                        int* __restrict__ bkt_cur) {
    __shared__ int ts[1024];
    int tid = threadIdx.x;
    int v = (tid < NBKT) ? bkt_cnt[tid] : 0;
    ts[tid] = v;
    __syncthreads();
    for (int off = 1; off < 1024; off <<= 1) {
        int t = (tid >= off) ? ts[tid - off] : 0;
        __syncthreads();
        ts[tid] += t;
        __syncthreads();
    }
    if (tid < NBKT) {
        int base = ts[tid] - v;
        bkt_ptr[tid] = base;
        bkt_cur[tid] = base;
    }
    if (tid == 0) bkt_ptr[NBKT] = NE;
}

// ---------------- pass 1: partition edges (packed: src | local<<17) ----------------
__global__ __launch_bounds__(256) void part_kernel(const int* __restrict__ src,
                                                   const int* __restrict__ dst,
                                                   int* __restrict__ bkt_cur,
                                                   int* __restrict__ epack) {
    __shared__ int hist[NBKT];
    __shared__ int cur[NBKT];
    int tid = threadIdx.x;
    int e0 = blockIdx.x * TILE;
    int e1 = min(e0 + TILE, NE);
    for (int i = tid; i < NBKT; i += 256) hist[i] = 0;
    __syncthreads();
    for (int e = e0 + tid; e < e1; e += 256)
        atomicAdd(&hist[dst[e] >> BSH], 1);
    __syncthreads();
    for (int i = tid; i < NBKT; i += 256) {
        int h = hist[i];
        cur[i] = h ? atomicAdd(&bkt_cur[i], h) : 0;  // global base of this block's range
    }
    __syncthreads();
    for (int e = e0 + tid; e < e1; e += 256) {
        int d = dst[e];
        int pos = atomicAdd(&cur[d >> BSH], 1);
        epack[pos] = src[e] | ((d & (NPB - 1)) << 17);
    }
}

// ---------------- pass 2: per-bucket fine CSR build (LDS only) ----------------
__global__ __launch_bounds__(256) void build_kernel(const int* __restrict__ epack,
                                                    const int* __restrict__ bkt_ptr,
                                                    int* __restrict__ row_ptr,
                                                    int* __restrict__ col,
                                                    float* __restrict__ deg_inv) {
    __shared__ int cnt[NPB];
    __shared__ int ts[NPB];
    int b = blockIdx.x;
    int tid = threadIdx.x;
    int ebase = bkt_ptr[b], eend = bkt_ptr[b + 1];
    int nbase = b << BSH;
    if (tid < NPB) cnt[tid] = 0;
    __syncthreads();
    for (int e = ebase + tid; e < eend; e += 256)
        atomicAdd(&cnt[epack[e] >> 17], 1);
    __syncthreads();
    int v = (tid < NPB) ? cnt[tid] : 0;
    if (tid < NPB) ts[tid] = v;
    __syncthreads();
    for (int off = 1; off < NPB; off <<= 1) {
        int t = (tid >= off && tid < NPB) ? ts[tid - off] : 0;
        __syncthreads();
        if (tid < NPB) ts[tid] += t;
        __syncthreads();
    }
    if (tid < NPB) {
        int loff = ts[tid] - v;
        int node = nbase + tid;
        if (node < NN) {
            row_ptr[node] = ebase + loff;
            deg_inv[node] = rsqrtf(1.0f + (float)v);
        }
        cnt[tid] = loff;  // reuse as cursor
    }
    if (b == 0 && tid == 0) row_ptr[NN] = NE;
    __syncthreads();
    for (int e = ebase + tid; e < eend; e += 256) {
        int rec = epack[e];
        int r = atomicAdd(&cnt[rec >> 17], 1);
        col[ebase + r] = rec & 0x1FFFF;
    }
}

// ---------------- GEMM1: [N,128]@[128,32], reg-tiled, bf16 output ----------------
// 32 rows/block; thread (r = tid>>3, c8 = (tid&7)*4) computes a 1x4 strip.
__global__ __launch_bounds__(256) void gemm_x_w1(const float* __restrict__ x,
                                                 const float* __restrict__ W,
                                                 const float* __restrict__ deg_inv,
                                                 unsigned short* __restrict__ h, int N) {
    __shared__ float wsh[128 * 32];      // 16 KB
    __shared__ float xs[32][132];        // pad 128->132: rows hit distinct banks
    int tid = threadIdx.x;
    int row0 = blockIdx.x * 32;
    for (int i = tid; i < 1024; i += 256)
        ((float4*)wsh)[i] = ((const float4*)W)[i];
    for (int i = tid; i < 1024; i += 256) {
        int r = i >> 5, c4 = i & 31;
        *(float4*)&xs[r][c4 * 4] = ((const float4*)(x + (size_t)(row0 + r) * 128))[c4];
    }
    __syncthreads();
    int r = tid >> 3;
    int c8 = (tid & 7) * 4;
    float acc0 = 0.f, acc1 = 0.f, acc2 = 0.f, acc3 = 0.f;
#pragma unroll
    for (int k0 = 0; k0 < 128; k0 += 4) {
        float4 xv = *(const float4*)&xs[r][k0];
#pragma unroll
        for (int j = 0; j < 4; ++j) {
            float xk = (&xv.x)[j];
            float4 wv = *(const float4*)&wsh[(k0 + j) * 32 + c8];
            acc0 += xk * wv.x;
            acc1 += xk * wv.y;
            acc2 += xk * wv.z;
            acc3 += xk * wv.w;
        }
    }
    float di = deg_inv[row0 + r];
    ushort4 o;
    o.x = f2bf(acc0 * di);
    o.y = f2bf(acc1 * di);
    o.z = f2bf(acc2 * di);
    o.w = f2bf(acc3 * di);
    *(ushort4*)&h[(size_t)(row0 + r) * 32 + c8] = o;
}

// ---------------- gather conv F=32 (bf16), one node per 16 lanes ----------------
// MODE 0: out_bf[node] = bf16( di^2*acc + di*b )   (feeds conv2)
// MODE 1: out_f32[node] = di*acc                   (feeds pooling)
template <int MODE>
__global__ __launch_bounds__(256) void conv_bf_kernel(const int* __restrict__ row_ptr,
                                                      const int* __restrict__ col,
                                                      const unsigned int* __restrict__ h,
                                                      const float* __restrict__ deg_inv,
                                                      const float* __restrict__ b,
                                                      unsigned int* __restrict__ out_bf,
                                                      float2* __restrict__ out_f32) {
    int gid = blockIdx.x * blockDim.x + threadIdx.x;
    int node = gid >> 4;
    int L = gid & 15;
    if (node >= NN) return;
    int beg = row_ptr[node], end = row_ptr[node + 1];
    float2 acc = bf2x2(h[node * 16 + L]);  // self loop
    for (int j0 = beg; j0 < end; j0 += 16) {
        int idx = j0 + L;
        int myc = (idx < end) ? col[idx] : 0;
        int m = end - j0;
        if (m > 16) m = 16;
        for (int t = 0; t < m; ++t) {
            int c = __shfl(myc, t, 16);
            float2 v = bf2x2(h[c * 16 + L]);
            acc.x += v.x;
            acc.y += v.y;
        }
    }
    float di = deg_inv[node];
    if (MODE == 0) {
        float ox = di * di * acc.x + di * b[2 * L];
        float oy = di * di * acc.y + di * b[2 * L + 1];
        out_bf[node * 16 + L] = (unsigned int)f2bf(ox) | ((unsigned int)f2bf(oy) << 16);
    } else {
        out_f32[node * 16 + L] = make_float2(di * acc.x, di * acc.y);
    }
}

// ---------------- pooling over F=32 (fp32 input) ----------------
__global__ void pool_kernel(const float* __restrict__ h, const int* __restrict__ batch,
                            float* __restrict__ gsum, float* __restrict__ gcnt, int N) {
    int t = blockIdx.x * blockDim.x + threadIdx.x;
    int chunk = t / 32;
    int f = t % 32;
    int n0 = chunk * 16;
    if (n0 >= N) return;
    int n1 = min(n0 + 16, N);
    int cur = batch[n0];
    float acc = 0.f, ccnt = 0.f;
    for (int n = n0; n < n1; ++n) {
        int b = batch[n];
        if (b != cur) {
            unsafeAtomicAdd(&gsum[cur * 32 + f], acc);
            if (f == 0) unsafeAtomicAdd(&gcnt[cur], ccnt);
            acc = 0.f; ccnt = 0.f; cur = b;
        }
        acc += h[(size_t)n * 32 + f];
        ccnt += 1.f;
    }
    unsafeAtomicAdd(&gsum[cur * 32 + f], acc);
    if (f == 0) unsafeAtomicAdd(&gcnt[cur], ccnt);
}

// ---------------- head: Wc fold + z=relu(p32@Wc+bc) -> BN -> fc2 -> softplus ----------------
__global__ __launch_bounds__(256) void head_kernel(const float* __restrict__ gsum,
                                                   const float* __restrict__ gcnt,
                                                   const float* __restrict__ W2,
                                                   const float* __restrict__ b2,
                                                   const float* __restrict__ fcW1,
                                                   const float* __restrict__ fcb1,
                                                   const float* __restrict__ gamma,
                                                   const float* __restrict__ beta,
                                                   const float* __restrict__ fcW2,
                                                   const float* __restrict__ fcb2,
                                                   float* __restrict__ out) {
    __shared__ float zs[NG][33];
    __shared__ float wcs[32 * 32];
    __shared__ float bcs[32];
    __shared__ float part1[8][32];
    __shared__ float part2[8][32];
    __shared__ float mu[32], rstd[32];
    int g = threadIdx.x;

    // fold Wc = W2@fcW1, bc = b2@fcW1+fcb1 directly into LDS
    for (int idx = g; idx < 32 * 32; idx += 256) {
        int k = idx / 32, ch = idx % 32;
        float a = 0.f;
#pragma unroll
        for (int j = 0; j < 64; ++j) a += W2[k * 64 + j] * fcW1[j * 32 + ch];
        wcs[idx] = a;
    }
    if (g < 32) {
        float a = fcb1[g];
#pragma unroll
        for (int j = 0; j < 64; ++j) a += b2[j] * fcW1[j * 32 + g];
        bcs[g] = a;
    }
    __syncthreads();

    float p32[32];
    float inv = 1.0f / fmaxf(gcnt[g], 1.0f);
    {
        const float4* gs4 = (const float4*)(gsum + g * 32);
#pragma unroll
        for (int q = 0; q < 8; ++q) {
            float4 v = gs4[q];
            p32[q * 4 + 0] = v.x * inv;
            p32[q * 4 + 1] = v.y * inv;
            p32[q * 4 + 2] = v.z * inv;
            p32[q * 4 + 3] = v.w * inv;
        }
    }
#pragma unroll 4
    for (int ch = 0; ch < 32; ++ch) {
        float acc = bcs[ch];
#pragma unroll
        for (int k = 0; k < 32; ++k) acc += p32[k] * wcs[k * 32 + ch];
        zs[g][ch] = fmaxf(acc, 0.f);
    }
    __syncthreads();

    {
        int ch = g & 31, seg = g >> 5;
        float s = 0.f, sq = 0.f;
#pragma unroll
        for (int i = 0; i < 32; ++i) {
            float v = zs[seg * 32 + i][ch];
            s += v;
            sq += v * v;
        }
        part1[seg][ch] = s;
        part2[seg][ch] = sq;
    }
    __syncthreads();
    if (g < 32) {
        float s = 0.f, sq = 0.f;
#pragma unroll
        for (int i = 0; i < 8; ++i) { s += part1[i][g]; sq += part2[i][g]; }
        float m = s / NG;
        float v = sq / NG - m * m;
        mu[g] = m;
        rstd[g] = rsqrtf(fmaxf(v, 0.f) + 1e-5f);
    }
    __syncthreads();

    float acc = fcb2[0];
#pragma unroll 4
    for (int ch = 0; ch < 32; ++ch) {
        float zn = (zs[g][ch] - mu[ch]) * rstd[ch] * gamma[ch] + beta[ch];
        acc += zn * fcW2[ch];
    }
    out[g] = fmaxf(acc, 0.f) + log1pf(expf(-fabsf(acc)));
}

extern "C" void kernel_launch(void* const* d_in, const int* in_sizes, int n_in,
                              void* d_out, int out_size, void* d_ws, size_t ws_size,
                              hipStream_t stream) {
    const float* x     = (const float*)d_in[0];
    const int*   ei    = (const int*)d_in[1];
    const int*   batch = (const int*)d_in[2];
    const float* W1    = (const float*)d_in[3];
    const float* b1    = (const float*)d_in[4];
    const float* W2    = (const float*)d_in[5];
    const float* b2    = (const float*)d_in[6];
    const float* fcW1  = (const float*)d_in[7];
    const float* fcb1  = (const float*)d_in[8];
    const float* gamma = (const float*)d_in[9];
    const float* beta  = (const float*)d_in[10];
    const float* fcW2  = (const float*)d_in[11];
    const float* fcb2  = (const float*)d_in[12];
    float* out = (float*)d_out;

    // workspace layout (all chunks 16B aligned)
    char* p = (char*)d_ws;
    int*   bkt_cnt = (int*)p;        p += 800 * 4;
    int*   bkt_ptr = (int*)p;        p += 800 * 4;
    int*   bkt_cur = (int*)p;        p += 800 * 4;
    float* deg_inv = (float*)p;      p += (size_t)NN * 4;
    int*   row_ptr = (int*)p;        p += (size_t)(NN + 8) * 4;
    int*   epack   = (int*)p;        p += (size_t)NE * 4;
    int*   col     = (int*)p;        p += (size_t)NE * 4;
    unsigned short* h1s = (unsigned short*)p;  p += (size_t)NN * 32 * 2;  // bf16
    unsigned int*   t1  = (unsigned int*)p;    p += (size_t)NN * 16 * 4;  // bf16x2
    float* agg2    = (float*)p;      p += (size_t)NN * 32 * 4;
    float* gsum    = (float*)p;      p += (size_t)NG * 32 * 4;
    float* gcnt    = (float*)p;      p += (size_t)NG * 4;

    const int* srcv = ei;
    const int* dstv = ei + NE;

    hipMemsetAsync(bkt_cnt, 0, NBKT * sizeof(int), stream);
    hipMemsetAsync(gsum, 0, (NG * 32 + NG) * sizeof(float), stream);

    // CSR build: count -> scan -> partition (packed) -> per-bucket build
    count_kernel<<<NB_P1, 256, 0, stream>>>(dstv, bkt_cnt);
    scan_bkt_kernel<<<1, 1024, 0, stream>>>(bkt_cnt, bkt_ptr, bkt_cur);
    part_kernel<<<NB_P1, 256, 0, stream>>>(srcv, dstv, bkt_cur, epack);
    build_kernel<<<NBKT, 256, 0, stream>>>(epack, bkt_ptr, row_ptr, col, deg_inv);

    // layer 1: h1s(bf16) = (x@W1)*deg_inv ; t1(bf16) = di^2*agg + di*b1
    gemm_x_w1<<<NN / 32, 256, 0, stream>>>(x, W1, deg_inv, h1s, NN);
    conv_bf_kernel<0><<<((size_t)NN * 16 + 255) / 256, 256, 0, stream>>>(
        row_ptr, col, (const unsigned int*)h1s, deg_inv, b1, t1, nullptr);

    // layer 2 aggregation (W2 folded into head): agg2(fp32) = di*agg
    conv_bf_kernel<1><<<((size_t)NN * 16 + 255) / 256, 256, 0, stream>>>(
        row_ptr, col, t1, deg_inv, b1, nullptr, (float2*)agg2);

    // pooling (F=32) + head (wc fold fused)
    pool_kernel<<<(((NN + 15) / 16) * 32 + 255) / 256, 256, 0, stream>>>(agg2, batch, gsum, gcnt, NN);
    head_kernel<<<1, 256, 0, stream>>>(gsum, gcnt, W2, b2, fcW1, fcb1, gamma, beta, fcW2, fcb2, out);
}

// Round 9
// 288.980 us; speedup vs baseline: 1.9873x; 1.0218x over previous
//
#include <hip/hip_runtime.h>

#define NN 100000
#define NE 1600000
#define NG 256

#define BSH 7                 // bucket = dst >> 7  (128 nodes/bucket)
#define NPB 128               // nodes per bucket
#define NBKT ((NN + NPB - 1) / NPB)   // 782
#define TILE 2048
#define NB_P1 ((NE + TILE - 1) / TILE) // 782

__device__ __forceinline__ unsigned short f2bf(float x) {
    unsigned int u = __float_as_uint(x);
    u += 0x7FFFu + ((u >> 16) & 1u);   // round-to-nearest-even
    return (unsigned short)(u >> 16);
}
__device__ __forceinline__ float2 bf2x2(unsigned int v) {
    float2 r;
    r.x = __uint_as_float(v << 16);
    r.y = __uint_as_float(v & 0xFFFF0000u);
    return r;
}

// ---------------- pass 0: count edges per coarse bucket ----------------
__global__ __launch_bounds__(256) void count_kernel(const int* __restrict__ dst,
                                                    int* __restrict__ bkt_cnt) {
    __shared__ int hist[NBKT];
    int tid = threadIdx.x;
    int e0 = blockIdx.x * TILE;
    int e1 = min(e0 + TILE, NE);
    for (int i = tid; i < NBKT; i += 256) hist[i] = 0;
    __syncthreads();
    for (int e = e0 + tid; e < e1; e += 256)
        atomicAdd(&hist[dst[e] >> BSH], 1);
    __syncthreads();
    for (int i = tid; i < NBKT; i += 256) {
        int h = hist[i];
        if (h) atomicAdd(&bkt_cnt[i], h);  // non-returning
    }
}

// ---------------- scan bucket counts -> bases + reservation cursors ----------------
__global__ __launch_bounds__(1024) void scan_bkt_kernel(const int* __restrict__ bkt_cnt,
                                                        int* __restrict__ bkt_ptr,
                                                        int* __restrict__ bkt_cur) {
    __shared__ int ts[1024];
    int tid = threadIdx.x;
    int v = (tid < NBKT) ? bkt_cnt[tid] : 0;
    ts[tid] = v;
    __syncthreads();
    for (int off = 1; off < 1024; off <<= 1) {
        int t = (tid >= off) ? ts[tid - off] : 0;
        __syncthreads();
        ts[tid] += t;
        __syncthreads();
    }
    if (tid < NBKT) {
        int base = ts[tid] - v;
        bkt_ptr[tid] = base;
        bkt_cur[tid] = base;
    }
    if (tid == 0) bkt_ptr[NBKT] = NE;
}

// ---------------- pass 1: partition edges (packed: src | local<<17) ----------------
__global__ __launch_bounds__(256) void part_kernel(const int* __restrict__ src,
                                                   const int* __restrict__ dst,
                                                   int* __restrict__ bkt_cur,
                                                   int* __restrict__ epack) {
    __shared__ int hist[NBKT];
    __shared__ int cur[NBKT];
    int tid = threadIdx.x;
    int e0 = blockIdx.x * TILE;
    int e1 = min(e0 + TILE, NE);
    for (int i = tid; i < NBKT; i += 256) hist[i] = 0;
    __syncthreads();
    for (int e = e0 + tid; e < e1; e += 256)
        atomicAdd(&hist[dst[e] >> BSH], 1);
    __syncthreads();
    for (int i = tid; i < NBKT; i += 256) {
        int h = hist[i];
        cur[i] = h ? atomicAdd(&bkt_cur[i], h) : 0;  // global base of this block's range
    }
    __syncthreads();
    for (int e = e0 + tid; e < e1; e += 256) {
        int d = dst[e];
        int pos = atomicAdd(&cur[d >> BSH], 1);
        epack[pos] = src[e] | ((d & (NPB - 1)) << 17);
    }
}

// ---------------- pass 2: per-bucket fine CSR build (LDS only) ----------------
__global__ __launch_bounds__(256) void build_kernel(const int* __restrict__ epack,
                                                    const int* __restrict__ bkt_ptr,
                                                    int* __restrict__ row_ptr,
                                                    int* __restrict__ col,
                                                    float* __restrict__ deg_inv) {
    __shared__ int cnt[NPB];
    __shared__ int ts[NPB];
    int b = blockIdx.x;
    int tid = threadIdx.x;
    int ebase = bkt_ptr[b], eend = bkt_ptr[b + 1];
    int nbase = b << BSH;
    if (tid < NPB) cnt[tid] = 0;
    __syncthreads();
    for (int e = ebase + tid; e < eend; e += 256)
        atomicAdd(&cnt[epack[e] >> 17], 1);
    __syncthreads();
    int v = (tid < NPB) ? cnt[tid] : 0;
    if (tid < NPB) ts[tid] = v;
    __syncthreads();
    for (int off = 1; off < NPB; off <<= 1) {
        int t = (tid >= off && tid < NPB) ? ts[tid - off] : 0;
        __syncthreads();
        if (tid < NPB) ts[tid] += t;
        __syncthreads();
    }
    if (tid < NPB) {
        int loff = ts[tid] - v;
        int node = nbase + tid;
        if (node < NN) {
            row_ptr[node] = ebase + loff;
            deg_inv[node] = rsqrtf(1.0f + (float)v);
        }
        cnt[tid] = loff;  // reuse as cursor
    }
    if (b == 0 && tid == 0) row_ptr[NN] = NE;
    __syncthreads();
    for (int e = ebase + tid; e < eend; e += 256) {
        int rec = epack[e];
        int r = atomicAdd(&cnt[rec >> 17], 1);
        col[ebase + r] = rec & 0x1FFFF;
    }
}

// ---------------- GEMM1: [N,128]@[128,32], reg-tiled, bf16 output ----------------
__global__ __launch_bounds__(256) void gemm_x_w1(const float* __restrict__ x,
                                                 const float* __restrict__ W,
                                                 const float* __restrict__ deg_inv,
                                                 unsigned short* __restrict__ h, int N) {
    __shared__ float wsh[128 * 32];      // 16 KB
    __shared__ float xs[32][132];        // pad 128->132: rows hit distinct banks
    int tid = threadIdx.x;
    int row0 = blockIdx.x * 32;
    for (int i = tid; i < 1024; i += 256)
        ((float4*)wsh)[i] = ((const float4*)W)[i];
    for (int i = tid; i < 1024; i += 256) {
        int r = i >> 5, c4 = i & 31;
        *(float4*)&xs[r][c4 * 4] = ((const float4*)(x + (size_t)(row0 + r) * 128))[c4];
    }
    __syncthreads();
    int r = tid >> 3;
    int c8 = (tid & 7) * 4;
    float acc0 = 0.f, acc1 = 0.f, acc2 = 0.f, acc3 = 0.f;
#pragma unroll
    for (int k0 = 0; k0 < 128; k0 += 4) {
        float4 xv = *(const float4*)&xs[r][k0];
#pragma unroll
        for (int j = 0; j < 4; ++j) {
            float xk = (&xv.x)[j];
            float4 wv = *(const float4*)&wsh[(k0 + j) * 32 + c8];
            acc0 += xk * wv.x;
            acc1 += xk * wv.y;
            acc2 += xk * wv.z;
            acc3 += xk * wv.w;
        }
    }
    float di = deg_inv[row0 + r];
    ushort4 o;
    o.x = f2bf(acc0 * di);
    o.y = f2bf(acc1 * di);
    o.z = f2bf(acc2 * di);
    o.w = f2bf(acc3 * di);
    *(ushort4*)&h[(size_t)(row0 + r) * 32 + c8] = o;
}

// ---------------- gather conv F=32 (bf16), one node per 16 lanes ----------------
// 4-deep load pipelining: independent accumulators keep 4 gathers in flight.
// MODE 0: out_bf[node] = bf16( di^2*acc + di*b )   (feeds conv2)
// MODE 1: out_f32[node] = di*acc                   (feeds pooling)
template <int MODE>
__global__ __launch_bounds__(256) void conv_bf_kernel(const int* __restrict__ row_ptr,
                                                      const int* __restrict__ col,
                                                      const unsigned int* __restrict__ h,
                                                      const float* __restrict__ deg_inv,
                                                      const float* __restrict__ b,
                                                      unsigned int* __restrict__ out_bf,
                                                      float2* __restrict__ out_f32) {
    int gid = blockIdx.x * blockDim.x + threadIdx.x;
    int node = gid >> 4;
    int L = gid & 15;
    if (node >= NN) return;
    int beg = row_ptr[node], end = row_ptr[node + 1];
    float2 a0 = bf2x2(h[node * 16 + L]);  // self loop
    float2 a1 = make_float2(0.f, 0.f);
    float2 a2 = make_float2(0.f, 0.f);
    float2 a3 = make_float2(0.f, 0.f);
    for (int j0 = beg; j0 < end; j0 += 16) {
        int idx = j0 + L;
        int myc = (idx < end) ? col[idx] : 0;
        int m = end - j0;
        if (m > 16) m = 16;
        int t = 0;
        for (; t + 4 <= m; t += 4) {
            int c0 = __shfl(myc, t, 16);
            int c1 = __shfl(myc, t + 1, 16);
            int c2 = __shfl(myc, t + 2, 16);
            int c3 = __shfl(myc, t + 3, 16);
            unsigned int v0 = h[c0 * 16 + L];
            unsigned int v1 = h[c1 * 16 + L];
            unsigned int v2 = h[c2 * 16 + L];
            unsigned int v3 = h[c3 * 16 + L];
            float2 f0 = bf2x2(v0), f1 = bf2x2(v1), f2 = bf2x2(v2), f3 = bf2x2(v3);
            a0.x += f0.x; a0.y += f0.y;
            a1.x += f1.x; a1.y += f1.y;
            a2.x += f2.x; a2.y += f2.y;
            a3.x += f3.x; a3.y += f3.y;
        }
        for (; t < m; ++t) {
            int c = __shfl(myc, t, 16);
            float2 v = bf2x2(h[c * 16 + L]);
            a0.x += v.x; a0.y += v.y;
        }
    }
    float2 acc;
    acc.x = (a0.x + a1.x) + (a2.x + a3.x);
    acc.y = (a0.y + a1.y) + (a2.y + a3.y);
    float di = deg_inv[node];
    if (MODE == 0) {
        float ox = di * di * acc.x + di * b[2 * L];
        float oy = di * di * acc.y + di * b[2 * L + 1];
        out_bf[node * 16 + L] = (unsigned int)f2bf(ox) | ((unsigned int)f2bf(oy) << 16);
    } else {
        out_f32[node * 16 + L] = make_float2(di * acc.x, di * acc.y);
    }
}

// ---------------- pooling over F=32 (fp32 input) ----------------
__global__ void pool_kernel(const float* __restrict__ h, const int* __restrict__ batch,
                            float* __restrict__ gsum, float* __restrict__ gcnt, int N) {
    int t = blockIdx.x * blockDim.x + threadIdx.x;
    int chunk = t / 32;
    int f = t % 32;
    int n0 = chunk * 16;
    if (n0 >= N) return;
    int n1 = min(n0 + 16, N);
    int cur = batch[n0];
    float acc = 0.f, ccnt = 0.f;
    for (int n = n0; n < n1; ++n) {
        int b = batch[n];
        if (b != cur) {
            unsafeAtomicAdd(&gsum[cur * 32 + f], acc);
            if (f == 0) unsafeAtomicAdd(&gcnt[cur], ccnt);
            acc = 0.f; ccnt = 0.f; cur = b;
        }
        acc += h[(size_t)n * 32 + f];
        ccnt += 1.f;
    }
    unsafeAtomicAdd(&gsum[cur * 32 + f], acc);
    if (f == 0) unsafeAtomicAdd(&gcnt[cur], ccnt);
}

// ---------------- head: Wc fold + z=relu(p32@Wc+bc) -> BN -> fc2 -> softplus ----------------
__global__ __launch_bounds__(256) void head_kernel(const float* __restrict__ gsum,
                                                   const float* __restrict__ gcnt,
                                                   const float* __restrict__ W2,
                                                   const float* __restrict__ b2,
                                                   const float* __restrict__ fcW1,
                                                   const float* __restrict__ fcb1,
                                                   const float* __restrict__ gamma,
                                                   const float* __restrict__ beta,
                                                   const float* __restrict__ fcW2,
                                                   const float* __restrict__ fcb2,
                                                   float* __restrict__ out) {
    __shared__ float zs[NG][33];
    __shared__ float wcs[32 * 32];
    __shared__ float bcs[32];
    __shared__ float part1[8][32];
    __shared__ float part2[8][32];
    __shared__ float mu[32], rstd[32];
    int g = threadIdx.x;

    // fold Wc = W2@fcW1, bc = b2@fcW1+fcb1 directly into LDS
    for (int idx = g; idx < 32 * 32; idx += 256) {
        int k = idx / 32, ch = idx % 32;
        float a = 0.f;
#pragma unroll
        for (int j = 0; j < 64; ++j) a += W2[k * 64 + j] * fcW1[j * 32 + ch];
        wcs[idx] = a;
    }
    if (g < 32) {
        float a = fcb1[g];
#pragma unroll
        for (int j = 0; j < 64; ++j) a += b2[j] * fcW1[j * 32 + g];
        bcs[g] = a;
    }
    __syncthreads();

    float p32[32];
    float inv = 1.0f / fmaxf(gcnt[g], 1.0f);
    {
        const float4* gs4 = (const float4*)(gsum + g * 32);
#pragma unroll
        for (int q = 0; q < 8; ++q) {
            float4 v = gs4[q];
            p32[q * 4 + 0] = v.x * inv;
            p32[q * 4 + 1] = v.y * inv;
            p32[q * 4 + 2] = v.z * inv;
            p32[q * 4 + 3] = v.w * inv;
        }
    }
#pragma unroll 4
    for (int ch = 0; ch < 32; ++ch) {
        float acc = bcs[ch];
#pragma unroll
        for (int k = 0; k < 32; ++k) acc += p32[k] * wcs[k * 32 + ch];
        zs[g][ch] = fmaxf(acc, 0.f);
    }
    __syncthreads();

    {
        int ch = g & 31, seg = g >> 5;
        float s = 0.f, sq = 0.f;
#pragma unroll
        for (int i = 0; i < 32; ++i) {
            float v = zs[seg * 32 + i][ch];
            s += v;
            sq += v * v;
        }
        part1[seg][ch] = s;
        part2[seg][ch] = sq;
    }
    __syncthreads();
    if (g < 32) {
        float s = 0.f, sq = 0.f;
#pragma unroll
        for (int i = 0; i < 8; ++i) { s += part1[i][g]; sq += part2[i][g]; }
        float m = s / NG;
        float v = sq / NG - m * m;
        mu[g] = m;
        rstd[g] = rsqrtf(fmaxf(v, 0.f) + 1e-5f);
    }
    __syncthreads();

    float acc = fcb2[0];
#pragma unroll 4
    for (int ch = 0; ch < 32; ++ch) {
        float zn = (zs[g][ch] - mu[ch]) * rstd[ch] * gamma[ch] + beta[ch];
        acc += zn * fcW2[ch];
    }
    out[g] = fmaxf(acc, 0.f) + log1pf(expf(-fabsf(acc)));
}

extern "C" void kernel_launch(void* const* d_in, const int* in_sizes, int n_in,
                              void* d_out, int out_size, void* d_ws, size_t ws_size,
                              hipStream_t stream) {
    const float* x     = (const float*)d_in[0];
    const int*   ei    = (const int*)d_in[1];
    const int*   batch = (const int*)d_in[2];
    const float* W1    = (const float*)d_in[3];
    const float* b1    = (const float*)d_in[4];
    const float* W2    = (const float*)d_in[5];
    const float* b2    = (const float*)d_in[6];
    const float* fcW1  = (const float*)d_in[7];
    const float* fcb1  = (const float*)d_in[8];
    const float* gamma = (const float*)d_in[9];
    const float* beta  = (const float*)d_in[10];
    const float* fcW2  = (const float*)d_in[11];
    const float* fcb2  = (const float*)d_in[12];
    float* out = (float*)d_out;

    // workspace layout (all chunks 16B aligned)
    char* p = (char*)d_ws;
    int*   bkt_cnt = (int*)p;        p += 800 * 4;
    int*   bkt_ptr = (int*)p;        p += 800 * 4;
    int*   bkt_cur = (int*)p;        p += 800 * 4;
    float* deg_inv = (float*)p;      p += (size_t)NN * 4;
    int*   row_ptr = (int*)p;        p += (size_t)(NN + 8) * 4;
    int*   epack   = (int*)p;        p += (size_t)NE * 4;
    int*   col     = (int*)p;        p += (size_t)NE * 4;
    unsigned short* h1s = (unsigned short*)p;  p += (size_t)NN * 32 * 2;  // bf16
    unsigned int*   t1  = (unsigned int*)p;    p += (size_t)NN * 16 * 4;  // bf16x2
    float* agg2    = (float*)p;      p += (size_t)NN * 32 * 4;
    float* gsum    = (float*)p;      p += (size_t)NG * 32 * 4;
    float* gcnt    = (float*)p;      p += (size_t)NG * 4;

    const int* srcv = ei;
    const int* dstv = ei + NE;

    hipMemsetAsync(bkt_cnt, 0, NBKT * sizeof(int), stream);
    hipMemsetAsync(gsum, 0, (NG * 32 + NG) * sizeof(float), stream);

    // CSR build: count -> scan -> partition (packed) -> per-bucket build
    count_kernel<<<NB_P1, 256, 0, stream>>>(dstv, bkt_cnt);
    scan_bkt_kernel<<<1, 1024, 0, stream>>>(bkt_cnt, bkt_ptr, bkt_cur);
    part_kernel<<<NB_P1, 256, 0, stream>>>(srcv, dstv, bkt_cur, epack);
    build_kernel<<<NBKT, 256, 0, stream>>>(epack, bkt_ptr, row_ptr, col, deg_inv);

    // layer 1: h1s(bf16) = (x@W1)*deg_inv ; t1(bf16) = di^2*agg + di*b1
    gemm_x_w1<<<NN / 32, 256, 0, stream>>>(x, W1, deg_inv, h1s, NN);
    conv_bf_kernel<0><<<((size_t)NN * 16 + 255) / 256, 256, 0, stream>>>(
        row_ptr, col, (const unsigned int*)h1s, deg_inv, b1, t1, nullptr);

    // layer 2 aggregation (W2 folded into head): agg2(fp32) = di*agg
    conv_bf_kernel<1><<<((size_t)NN * 16 + 255) / 256, 256, 0, stream>>>(
        row_ptr, col, t1, deg_inv, b1, nullptr, (float2*)agg2);

    // pooling (F=32) + head (wc fold fused)
    pool_kernel<<<(((NN + 15) / 16) * 32 + 255) / 256, 256, 0, stream>>>(agg2, batch, gsum, gcnt, NN);
    head_kernel<<<1, 256, 0, stream>>>(gsum, gcnt, W2, b2, fcW1, fcb1, gamma, beta, fcW2, fcb2, out);
}

// Round 10
// 263.054 us; speedup vs baseline: 2.1831x; 1.0986x over previous
//
#include <hip/hip_runtime.h>

#define NN 100000
#define NE 1600000
#define NG 256

#define BSH 8                 // bucket = dst >> 8  (256 nodes/bucket)
#define NPB 256               // nodes per bucket
#define NBKT ((NN + NPB - 1) / NPB)   // 391
#define TILE 8192
#define NB_P1 ((NE + TILE - 1) / TILE) // 196

__device__ __forceinline__ unsigned short f2bf(float x) {
    unsigned int u = __float_as_uint(x);
    u += 0x7FFFu + ((u >> 16) & 1u);   // round-to-nearest-even
    return (unsigned short)(u >> 16);
}
__device__ __forceinline__ float2 bf2x2(unsigned int v) {
    float2 r;
    r.x = __uint_as_float(v << 16);
    r.y = __uint_as_float(v & 0xFFFF0000u);
    return r;
}

// ---------------- pass 0: count edges per coarse bucket ----------------
__global__ __launch_bounds__(1024) void count_kernel(const int* __restrict__ dst,
                                                     int* __restrict__ bkt_cnt) {
    __shared__ int hist[NBKT];
    int tid = threadIdx.x;
    int e0 = blockIdx.x * TILE;
    int e1 = min(e0 + TILE, NE);
    for (int i = tid; i < NBKT; i += 1024) hist[i] = 0;
    __syncthreads();
    for (int e = e0 + tid; e < e1; e += 1024)
        atomicAdd(&hist[dst[e] >> BSH], 1);
    __syncthreads();
    for (int i = tid; i < NBKT; i += 1024) {
        int h = hist[i];
        if (h) atomicAdd(&bkt_cnt[i], h);  // non-returning
    }
}

// ---------------- scan bucket counts -> bases + reservation cursors ----------------
__global__ __launch_bounds__(1024) void scan_bkt_kernel(const int* __restrict__ bkt_cnt,
                                                        int* __restrict__ bkt_ptr,
                                                        int* __restrict__ bkt_cur) {
    __shared__ int ts[1024];
    int tid = threadIdx.x;
    int v = (tid < NBKT) ? bkt_cnt[tid] : 0;
    ts[tid] = v;
    __syncthreads();
    for (int off = 1; off < 1024; off <<= 1) {
        int t = (tid >= off) ? ts[tid - off] : 0;
        __syncthreads();
        ts[tid] += t;
        __syncthreads();
    }
    if (tid < NBKT) {
        int base = ts[tid] - v;
        bkt_ptr[tid] = base;
        bkt_cur[tid] = base;
    }
    if (tid == 0) bkt_ptr[NBKT] = NE;
}

// ---------------- pass 1: partition edges (packed: src | local<<17) ----------------
__global__ __launch_bounds__(1024) void part_kernel(const int* __restrict__ src,
                                                    const int* __restrict__ dst,
                                                    int* __restrict__ bkt_cur,
                                                    int* __restrict__ epack) {
    __shared__ int hist[NBKT];
    __shared__ int cur[NBKT];
    int tid = threadIdx.x;
    int e0 = blockIdx.x * TILE;
    int e1 = min(e0 + TILE, NE);
    for (int i = tid; i < NBKT; i += 1024) hist[i] = 0;
    __syncthreads();
    for (int e = e0 + tid; e < e1; e += 1024)
        atomicAdd(&hist[dst[e] >> BSH], 1);
    __syncthreads();
    for (int i = tid; i < NBKT; i += 1024) {
        int h = hist[i];
        cur[i] = h ? atomicAdd(&bkt_cur[i], h) : 0;  // global base of this block's range
    }
    __syncthreads();
    for (int e = e0 + tid; e < e1; e += 1024) {
        int d = dst[e];
        int pos = atomicAdd(&cur[d >> BSH], 1);
        epack[pos] = src[e] | ((d & (NPB - 1)) << 17);
    }
}

// ---------------- pass 2: per-bucket fine CSR build (LDS only) ----------------
__global__ __launch_bounds__(256) void build_kernel(const int* __restrict__ epack,
                                                    const int* __restrict__ bkt_ptr,
                                                    int* __restrict__ row_ptr,
                                                    int* __restrict__ col,
                                                    float* __restrict__ deg_inv) {
    __shared__ int cnt[NPB];
    __shared__ int ts[NPB];
    int b = blockIdx.x;
    int tid = threadIdx.x;
    int ebase = bkt_ptr[b], eend = bkt_ptr[b + 1];
    int nbase = b << BSH;
    cnt[tid] = 0;
    __syncthreads();
    for (int e = ebase + tid; e < eend; e += 256)
        atomicAdd(&cnt[epack[e] >> 17], 1);
    __syncthreads();
    int v = cnt[tid];
    ts[tid] = v;
    __syncthreads();
    for (int off = 1; off < NPB; off <<= 1) {
        int t = (tid >= off) ? ts[tid - off] : 0;
        __syncthreads();
        ts[tid] += t;
        __syncthreads();
    }
    {
        int loff = ts[tid] - v;
        int node = nbase + tid;
        if (node < NN) {
            row_ptr[node] = ebase + loff;
            deg_inv[node] = rsqrtf(1.0f + (float)v);
        }
        cnt[tid] = loff;  // reuse as cursor
    }
    if (b == 0 && tid == 0) row_ptr[NN] = NE;
    __syncthreads();
    for (int e = ebase + tid; e < eend; e += 256) {
        int rec = epack[e];
        int r = atomicAdd(&cnt[rec >> 17], 1);
        col[ebase + r] = rec & 0x1FFFF;
    }
}

// ---------------- GEMM1: [N,128]@[128,32], reg-tiled, bf16 output ----------------
__global__ __launch_bounds__(256) void gemm_x_w1(const float* __restrict__ x,
                                                 const float* __restrict__ W,
                                                 const float* __restrict__ deg_inv,
                                                 unsigned short* __restrict__ h, int N) {
    __shared__ float wsh[128 * 32];      // 16 KB
    __shared__ float xs[32][132];        // pad 128->132: rows hit distinct banks
    int tid = threadIdx.x;
    int row0 = blockIdx.x * 32;
    for (int i = tid; i < 1024; i += 256)
        ((float4*)wsh)[i] = ((const float4*)W)[i];
    for (int i = tid; i < 1024; i += 256) {
        int r = i >> 5, c4 = i & 31;
        *(float4*)&xs[r][c4 * 4] = ((const float4*)(x + (size_t)(row0 + r) * 128))[c4];
    }
    __syncthreads();
    int r = tid >> 3;
    int c8 = (tid & 7) * 4;
    float acc0 = 0.f, acc1 = 0.f, acc2 = 0.f, acc3 = 0.f;
#pragma unroll
    for (int k0 = 0; k0 < 128; k0 += 4) {
        float4 xv = *(const float4*)&xs[r][k0];
#pragma unroll
        for (int j = 0; j < 4; ++j) {
            float xk = (&xv.x)[j];
            float4 wv = *(const float4*)&wsh[(k0 + j) * 32 + c8];
            acc0 += xk * wv.x;
            acc1 += xk * wv.y;
            acc2 += xk * wv.z;
            acc3 += xk * wv.w;
        }
    }
    float di = deg_inv[row0 + r];
    ushort4 o;
    o.x = f2bf(acc0 * di);
    o.y = f2bf(acc1 * di);
    o.z = f2bf(acc2 * di);
    o.w = f2bf(acc3 * di);
    *(ushort4*)&h[(size_t)(row0 + r) * 32 + c8] = o;
}

// ---------------- gather conv F=32 (bf16), one node per 16 lanes ----------------
// 4-deep load pipelining: independent accumulators keep 4 gathers in flight.
// MODE 0: out_bf[node] = bf16( di^2*acc + di*b )   (feeds conv2)
// MODE 1: out_f32[node] = di*acc                   (feeds pooling)
template <int MODE>
__global__ __launch_bounds__(256) void conv_bf_kernel(const int* __restrict__ row_ptr,
                                                      const int* __restrict__ col,
                                                      const unsigned int* __restrict__ h,
                                                      const float* __restrict__ deg_inv,
                                                      const float* __restrict__ b,
                                                      unsigned int* __restrict__ out_bf,
                                                      float2* __restrict__ out_f32) {
    int gid = blockIdx.x * blockDim.x + threadIdx.x;
    int node = gid >> 4;
    int L = gid & 15;
    if (node >= NN) return;
    int beg = row_ptr[node], end = row_ptr[node + 1];
    float2 a0 = bf2x2(h[node * 16 + L]);  // self loop
    float2 a1 = make_float2(0.f, 0.f);
    float2 a2 = make_float2(0.f, 0.f);
    float2 a3 = make_float2(0.f, 0.f);
    for (int j0 = beg; j0 < end; j0 += 16) {
        int idx = j0 + L;
        int myc = (idx < end) ? col[idx] : 0;
        int m = end - j0;
        if (m > 16) m = 16;
        int t = 0;
        for (; t + 4 <= m; t += 4) {
            int c0 = __shfl(myc, t, 16);
            int c1 = __shfl(myc, t + 1, 16);
            int c2 = __shfl(myc, t + 2, 16);
            int c3 = __shfl(myc, t + 3, 16);
            unsigned int v0 = h[c0 * 16 + L];
            unsigned int v1 = h[c1 * 16 + L];
            unsigned int v2 = h[c2 * 16 + L];
            unsigned int v3 = h[c3 * 16 + L];
            float2 f0 = bf2x2(v0), f1 = bf2x2(v1), f2 = bf2x2(v2), f3 = bf2x2(v3);
            a0.x += f0.x; a0.y += f0.y;
            a1.x += f1.x; a1.y += f1.y;
            a2.x += f2.x; a2.y += f2.y;
            a3.x += f3.x; a3.y += f3.y;
        }
        for (; t < m; ++t) {
            int c = __shfl(myc, t, 16);
            float2 v = bf2x2(h[c * 16 + L]);
            a0.x += v.x; a0.y += v.y;
        }
    }
    float2 acc;
    acc.x = (a0.x + a1.x) + (a2.x + a3.x);
    acc.y = (a0.y + a1.y) + (a2.y + a3.y);
    float di = deg_inv[node];
    if (MODE == 0) {
        float ox = di * di * acc.x + di * b[2 * L];
        float oy = di * di * acc.y + di * b[2 * L + 1];
        out_bf[node * 16 + L] = (unsigned int)f2bf(ox) | ((unsigned int)f2bf(oy) << 16);
    } else {
        out_f32[node * 16 + L] = make_float2(di * acc.x, di * acc.y);
    }
}

// ---------------- pooling over F=32 (fp32 input) ----------------
__global__ void pool_kernel(const float* __restrict__ h, const int* __restrict__ batch,
                            float* __restrict__ gsum, float* __restrict__ gcnt, int N) {
    int t = blockIdx.x * blockDim.x + threadIdx.x;
    int chunk = t / 32;
    int f = t % 32;
    int n0 = chunk * 16;
    if (n0 >= N) return;
    int n1 = min(n0 + 16, N);
    int cur = batch[n0];
    float acc = 0.f, ccnt = 0.f;
    for (int n = n0; n < n1; ++n) {
        int b = batch[n];
        if (b != cur) {
            unsafeAtomicAdd(&gsum[cur * 32 + f], acc);
            if (f == 0) unsafeAtomicAdd(&gcnt[cur], ccnt);
            acc = 0.f; ccnt = 0.f; cur = b;
        }
        acc += h[(size_t)n * 32 + f];
        ccnt += 1.f;
    }
    unsafeAtomicAdd(&gsum[cur * 32 + f], acc);
    if (f == 0) unsafeAtomicAdd(&gcnt[cur], ccnt);
}

// ---------------- head: Wc fold + z=relu(p32@Wc+bc) -> BN -> fc2 -> softplus ----------------
__global__ __launch_bounds__(256) void head_kernel(const float* __restrict__ gsum,
                                                   const float* __restrict__ gcnt,
                                                   const float* __restrict__ W2,
                                                   const float* __restrict__ b2,
                                                   const float* __restrict__ fcW1,
                                                   const float* __restrict__ fcb1,
                                                   const float* __restrict__ gamma,
                                                   const float* __restrict__ beta,
                                                   const float* __restrict__ fcW2,
                                                   const float* __restrict__ fcb2,
                                                   float* __restrict__ out) {
    __shared__ float zs[NG][33];
    __shared__ float wcs[32 * 32];
    __shared__ float bcs[32];
    __shared__ float part1[8][32];
    __shared__ float part2[8][32];
    __shared__ float mu[32], rstd[32];
    int g = threadIdx.x;

    // fold Wc = W2@fcW1, bc = b2@fcW1+fcb1 directly into LDS
    for (int idx = g; idx < 32 * 32; idx += 256) {
        int k = idx / 32, ch = idx % 32;
        float a = 0.f;
#pragma unroll
        for (int j = 0; j < 64; ++j) a += W2[k * 64 + j] * fcW1[j * 32 + ch];
        wcs[idx] = a;
    }
    if (g < 32) {
        float a = fcb1[g];
#pragma unroll
        for (int j = 0; j < 64; ++j) a += b2[j] * fcW1[j * 32 + g];
        bcs[g] = a;
    }
    __syncthreads();

    float p32[32];
    float inv = 1.0f / fmaxf(gcnt[g], 1.0f);
    {
        const float4* gs4 = (const float4*)(gsum + g * 32);
#pragma unroll
        for (int q = 0; q < 8; ++q) {
            float4 v = gs4[q];
            p32[q * 4 + 0] = v.x * inv;
            p32[q * 4 + 1] = v.y * inv;
            p32[q * 4 + 2] = v.z * inv;
            p32[q * 4 + 3] = v.w * inv;
        }
    }
#pragma unroll 4
    for (int ch = 0; ch < 32; ++ch) {
        float acc = bcs[ch];
#pragma unroll
        for (int k = 0; k < 32; ++k) acc += p32[k] * wcs[k * 32 + ch];
        zs[g][ch] = fmaxf(acc, 0.f);
    }
    __syncthreads();

    {
        int ch = g & 31, seg = g >> 5;
        float s = 0.f, sq = 0.f;
#pragma unroll
        for (int i = 0; i < 32; ++i) {
            float v = zs[seg * 32 + i][ch];
            s += v;
            sq += v * v;
        }
        part1[seg][ch] = s;
        part2[seg][ch] = sq;
    }
    __syncthreads();
    if (g < 32) {
        float s = 0.f, sq = 0.f;
#pragma unroll
        for (int i = 0; i < 8; ++i) { s += part1[i][g]; sq += part2[i][g]; }
        float m = s / NG;
        float v = sq / NG - m * m;
        mu[g] = m;
        rstd[g] = rsqrtf(fmaxf(v, 0.f) + 1e-5f);
    }
    __syncthreads();

    float acc = fcb2[0];
#pragma unroll 4
    for (int ch = 0; ch < 32; ++ch) {
        float zn = (zs[g][ch] - mu[ch]) * rstd[ch] * gamma[ch] + beta[ch];
        acc += zn * fcW2[ch];
    }
    out[g] = fmaxf(acc, 0.f) + log1pf(expf(-fabsf(acc)));
}

extern "C" void kernel_launch(void* const* d_in, const int* in_sizes, int n_in,
                              void* d_out, int out_size, void* d_ws, size_t ws_size,
                              hipStream_t stream) {
    const float* x     = (const float*)d_in[0];
    const int*   ei    = (const int*)d_in[1];
    const int*   batch = (const int*)d_in[2];
    const float* W1    = (const float*)d_in[3];
    const float* b1    = (const float*)d_in[4];
    const float* W2    = (const float*)d_in[5];
    const float* b2    = (const float*)d_in[6];
    const float* fcW1  = (const float*)d_in[7];
    const float* fcb1  = (const float*)d_in[8];
    const float* gamma = (const float*)d_in[9];
    const float* beta  = (const float*)d_in[10];
    const float* fcW2  = (const float*)d_in[11];
    const float* fcb2  = (const float*)d_in[12];
    float* out = (float*)d_out;

    // workspace layout (all chunks 16B aligned)
    char* p = (char*)d_ws;
    int*   bkt_cnt = (int*)p;        p += 400 * 4;
    int*   bkt_ptr = (int*)p;        p += 400 * 4;
    int*   bkt_cur = (int*)p;        p += 400 * 4;
    float* deg_inv = (float*)p;      p += (size_t)NN * 4;
    int*   row_ptr = (int*)p;        p += (size_t)(NN + 8) * 4;
    int*   epack   = (int*)p;        p += (size_t)NE * 4;
    int*   col     = (int*)p;        p += (size_t)NE * 4;
    unsigned short* h1s = (unsigned short*)p;  p += (size_t)NN * 32 * 2;  // bf16
    unsigned int*   t1  = (unsigned int*)p;    p += (size_t)NN * 16 * 4;  // bf16x2
    float* agg2    = (float*)p;      p += (size_t)NN * 32 * 4;
    float* gsum    = (float*)p;      p += (size_t)NG * 32 * 4;
    float* gcnt    = (float*)p;      p += (size_t)NG * 4;

    const int* srcv = ei;
    const int* dstv = ei + NE;

    hipMemsetAsync(bkt_cnt, 0, NBKT * sizeof(int), stream);
    hipMemsetAsync(gsum, 0, (NG * 32 + NG) * sizeof(float), stream);

    // CSR build: count -> scan -> partition (packed) -> per-bucket build
    count_kernel<<<NB_P1, 1024, 0, stream>>>(dstv, bkt_cnt);
    scan_bkt_kernel<<<1, 1024, 0, stream>>>(bkt_cnt, bkt_ptr, bkt_cur);
    part_kernel<<<NB_P1, 1024, 0, stream>>>(srcv, dstv, bkt_cur, epack);
    build_kernel<<<NBKT, 256, 0, stream>>>(epack, bkt_ptr, row_ptr, col, deg_inv);

    // layer 1: h1s(bf16) = (x@W1)*deg_inv ; t1(bf16) = di^2*agg + di*b1
    gemm_x_w1<<<NN / 32, 256, 0, stream>>>(x, W1, deg_inv, h1s, NN);
    conv_bf_kernel<0><<<((size_t)NN * 16 + 255) / 256, 256, 0, stream>>>(
        row_ptr, col, (const unsigned int*)h1s, deg_inv, b1, t1, nullptr);

    // layer 2 aggregation (W2 folded into head): agg2(fp32) = di*agg
    conv_bf_kernel<1><<<((size_t)NN * 16 + 255) / 256, 256, 0, stream>>>(
        row_ptr, col, t1, deg_inv, b1, nullptr, (float2*)agg2);

    // pooling (F=32) + head (wc fold fused)
    pool_kernel<<<(((NN + 15) / 16) * 32 + 255) / 256, 256, 0, stream>>>(agg2, batch, gsum, gcnt, NN);
    head_kernel<<<1, 256, 0, stream>>>(gsum, gcnt, W2, b2, fcW1, fcb1, gamma, beta, fcW2, fcb2, out);
}